// Round 3
// baseline (422.134 us; speedup 1.0000x reference)
//
#include <hip/hip_runtime.h>
#include <hip/hip_bf16.h>
#include <math.h>

// Problem constants
#define S 768
#define E 512
#define H 8
#define DK 64
#define TOPK 384

#define TN 64
#define BK 16

// ---------------------------------------------------------------------------
// Templated fp32 GEMM tile (bias added), float4 LDS reads.
// C[m0:m0+TMT, n0:n0+64] = A[m0:, :K] @ W[:K, n0:] + bias  (W row-major KxN)
// 256 threads; per-thread (TMT/16) x 4 accumulators.
// ---------------------------------------------------------------------------
template <int TMT>
__device__ __forceinline__ void gemm_tile(
    const float* __restrict__ A, const float* __restrict__ W,
    const float* __restrict__ bias, float* __restrict__ C,
    int N, int K, int m0, int n0) {
  constexpr int RM = TMT / 16;                 // rows per thread
  __shared__ __align__(16) float As[BK][TMT + 8];   // [k][m]
  __shared__ __align__(16) float Ws[BK][68];        // [k][n]
  const int tid = threadIdx.x;
  const int tm = (tid >> 4) * RM;
  const int tn = (tid & 15) << 2;
  const int wr = tid >> 4;            // 0..15 (W k-row)
  const int wc = tid & 15;            // float4 index along n
  const bool fullN = (n0 + TN <= N);
  float acc[RM][4] = {};
  for (int k0 = 0; k0 < K; k0 += BK) {
    // A tile TMT x 16, store transposed As[k][m]
    if (tid < TMT * 4) {
      int am = tid >> 2, ac = tid & 3;
      float4 av = *(const float4*)(A + (m0 + am) * K + k0 + ac * 4);
      As[ac * 4 + 0][am] = av.x;
      As[ac * 4 + 1][am] = av.y;
      As[ac * 4 + 2][am] = av.z;
      As[ac * 4 + 3][am] = av.w;
    }
    // W tile 16 x 64
    if (fullN) {
      *(float4*)&Ws[wr][wc * 4] = *(const float4*)(W + (k0 + wr) * N + n0 + wc * 4);
    } else {
      #pragma unroll
      for (int j = 0; j < 4; ++j) {
        int n = n0 + wc * 4 + j;
        Ws[wr][wc * 4 + j] = (n < N) ? W[(k0 + wr) * N + n] : 0.0f;
      }
    }
    __syncthreads();
    #pragma unroll
    for (int k = 0; k < BK; ++k) {
      float ar[RM];
      #pragma unroll
      for (int x = 0; x < RM; ++x) ar[x] = As[k][tm + x];
      float4 w4 = *(const float4*)&Ws[k][tn];
      float wv[4] = {w4.x, w4.y, w4.z, w4.w};
      #pragma unroll
      for (int x = 0; x < RM; ++x)
        #pragma unroll
        for (int y = 0; y < 4; ++y)
          acc[x][y] = fmaf(ar[x], wv[y], acc[x][y]);
    }
    __syncthreads();
  }
  #pragma unroll
  for (int x = 0; x < RM; ++x) {
    int m = m0 + tm + x;
    #pragma unroll
    for (int y = 0; y < 4; ++y) {
      int n = n0 + tn + y;
      if (n < N) C[m * N + n] = acc[x][y] + bias[n];
    }
  }
}

// ---------------------------------------------------------------------------
// Fused projections, TM=32: [Wq|Wk|Wv|iqW] (8 n-tiles each) + ikW + wpW.
// blockIdx.x in [0,34), blockIdx.y in [0,24).
// ---------------------------------------------------------------------------
struct SegTable {
  const float* W[6];
  const float* b[6];
  float*       out[6];
};

__global__ __launch_bounds__(256) void fused_proj_kernel(
    const float* __restrict__ A, SegTable tab) {
  int bx = blockIdx.x;
  int seg, nt;
  if (bx < 32) { seg = bx >> 3; nt = bx & 7; }
  else         { seg = 4 + (bx - 32); nt = 0; }
  const int N = (seg < 4) ? 512 : (seg == 4 ? 64 : 8);
  gemm_tile<32>(A, tab.W[seg], tab.b[seg], tab.out[seg], N, E,
                blockIdx.y * 32, nt * TN);
}

__global__ __launch_bounds__(256) void gemm_bias32(
    const float* __restrict__ A, const float* __restrict__ W,
    const float* __restrict__ bias, float* __restrict__ C, int N, int K) {
  gemm_tile<32>(A, W, bias, C, N, K, blockIdx.y * 32, blockIdx.x * TN);
}

// ---------------------------------------------------------------------------
// Indexer: ISC[s][t] = sum_h relu( dot64(QI[s, h*64:], KI[t, :]) ) * WI[s][h]
// Tile 32(s) x 64(t), 256 threads, 2x4 per thread.
// ---------------------------------------------------------------------------
__global__ __launch_bounds__(256) void indexer_kernel(
    const float* __restrict__ QI,   // S x 512 (cols head-major)
    const float* __restrict__ KI,   // S x 64
    const float* __restrict__ WI,   // S x 8
    float* __restrict__ ISC) {      // S x S
  __shared__ __align__(16) float ks[DK][68];   // [d][t]
  __shared__ __align__(16) float qs[DK][36];   // [d][s]
  const int tid = threadIdx.x;
  const int s0 = blockIdx.y * 32;
  const int t0 = blockIdx.x * 64;
  {
    int t = tid >> 2;
    int cb = tid & 3;
    #pragma unroll
    for (int cc = 0; cc < 4; ++cc) {
      int c = cb + cc * 4;
      float4 kv = *(const float4*)(KI + (t0 + t) * DK + c * 4);
      ks[c * 4 + 0][t] = kv.x;
      ks[c * 4 + 1][t] = kv.y;
      ks[c * 4 + 2][t] = kv.z;
      ks[c * 4 + 3][t] = kv.w;
    }
  }
  const int si = (tid >> 4) * 2;
  const int ti = (tid & 15) * 4;
  float acc[2][4] = {};
  for (int h = 0; h < H; ++h) {
    __syncthreads();
    #pragma unroll
    for (int r = 0; r < 2; ++r) {
      int idx = tid + r * 256;
      int s = idx >> 4;
      int c = idx & 15;
      float4 qv = *(const float4*)(QI + (s0 + s) * E + h * DK + c * 4);
      qs[c * 4 + 0][s] = qv.x;
      qs[c * 4 + 1][s] = qv.y;
      qs[c * 4 + 2][s] = qv.z;
      qs[c * 4 + 3][s] = qv.w;
    }
    __syncthreads();
    float dot[2][4] = {};
    #pragma unroll
    for (int d = 0; d < DK; ++d) {
      float4 kv = *(const float4*)&ks[d][ti];
      float kr[4] = {kv.x, kv.y, kv.z, kv.w};
      float q0 = qs[d][si];
      float q1 = qs[d][si + 1];
      #pragma unroll
      for (int j = 0; j < 4; ++j) {
        dot[0][j] = fmaf(q0, kr[j], dot[0][j]);
        dot[1][j] = fmaf(q1, kr[j], dot[1][j]);
      }
    }
    float w0 = WI[(s0 + si) * H + h];
    float w1 = WI[(s0 + si + 1) * H + h];
    #pragma unroll
    for (int j = 0; j < 4; ++j) {
      acc[0][j] += fmaxf(dot[0][j], 0.0f) * w0;
      acc[1][j] += fmaxf(dot[1][j], 0.0f) * w1;
    }
  }
  #pragma unroll
  for (int i = 0; i < 2; ++i) {
    float4 o = {acc[i][0], acc[i][1], acc[i][2], acc[i][3]};
    *(float4*)(ISC + (s0 + si + i) * S + t0 + ti) = o;
  }
}

// ---------------------------------------------------------------------------
// Top-k via bitonic sort (desc value, asc index ties == jax.lax.top_k).
// ---------------------------------------------------------------------------
__global__ __launch_bounds__(512) void topk_kernel(
    const float* __restrict__ ISC, int* __restrict__ TK) {
  __shared__ float v[1024];
  __shared__ int   ix[1024];
  const int s = blockIdx.x;
  const int tid = threadIdx.x;
  for (int i = tid; i < 1024; i += 512) {
    v[i] = (i < S) ? ISC[s * S + i] : -3.402823466e38f;
    ix[i] = i;
  }
  __syncthreads();
  for (int k = 2; k <= 1024; k <<= 1) {
    for (int j = k >> 1; j > 0; j >>= 1) {
      #pragma unroll
      for (int t = tid; t < 1024; t += 512) {
        int l = t ^ j;
        if (l > t) {
          float vt = v[t], vl = v[l];
          int it = ix[t], il = ix[l];
          bool l_before_t = (vl > vt) || (vl == vt && il < it);
          bool up = ((t & k) == 0);
          if (up ? l_before_t : !l_before_t) {
            v[t] = vl; v[l] = vt;
            ix[t] = il; ix[l] = it;
          }
        }
      }
      __syncthreads();
    }
  }
  if (tid < TOPK) TK[s * TOPK + tid] = ix[tid];
}

// ---------------------------------------------------------------------------
// Sparse attention: one block per (head, token). 256 threads = 4 waves.
// Score: wave-per-key (lane=dim, coalesced 256B K row, shuffle-reduce).
// V: thread (g,d), keys strided by 4, LDS reduce over g.
// ---------------------------------------------------------------------------
__global__ __launch_bounds__(256) void attn_kernel(
    const float* __restrict__ Q, const float* __restrict__ K,
    const float* __restrict__ V, const int* __restrict__ TK,
    float* __restrict__ ATT) {
  __shared__ float sc[TOPK];
  __shared__ int   tk[TOPK];
  __shared__ float qsh[DK];
  __shared__ float red[4][DK];
  __shared__ float wred[4];
  const int h = blockIdx.x;
  const int s = blockIdx.y;
  const int tid = threadIdx.x;
  const int lane = tid & 63;
  const int wave = tid >> 6;

  for (int i = tid; i < TOPK; i += 256) tk[i] = TK[s * TOPK + i];
  if (tid < DK) qsh[tid] = Q[s * E + h * DK + tid];
  __syncthreads();

  // ---- scores: one wave per key, lane = dim ----
  const float qd = qsh[lane];
  #pragma unroll 4
  for (int kk = wave; kk < TOPK; kk += 4) {
    int t = tk[kk];
    float p = qd * K[t * E + h * DK + lane];
    #pragma unroll
    for (int off = 32; off > 0; off >>= 1) p += __shfl_xor(p, off);
    if (lane == 0) sc[kk] = p * 0.125f;
  }
  __syncthreads();

  // ---- softmax over sc[0..383] ----
  float m = -3.402823466e38f;
  {
    float a = sc[tid];
    float b = (tid < TOPK - 256) ? sc[tid + 256] : -3.402823466e38f;
    m = fmaxf(a, b);
  }
  #pragma unroll
  for (int off = 32; off > 0; off >>= 1) m = fmaxf(m, __shfl_xor(m, off));
  if (lane == 0) wred[wave] = m;
  __syncthreads();
  m = fmaxf(fmaxf(wred[0], wred[1]), fmaxf(wred[2], wred[3]));

  float psum = 0.0f;
  {
    float e = expf(sc[tid] - m);
    sc[tid] = e;
    psum = e;
    if (tid < TOPK - 256) {
      float e2 = expf(sc[tid + 256] - m);
      sc[tid + 256] = e2;
      psum += e2;
    }
  }
  #pragma unroll
  for (int off = 32; off > 0; off >>= 1) psum += __shfl_xor(psum, off);
  __syncthreads();   // sc[] exp values visible to all
  if (lane == 0) wred[wave] = psum;
  __syncthreads();
  const float inv = 1.0f / (wred[0] + wred[1] + wred[2] + wred[3]);

  // ---- V accumulation: thread (g=wave, d=lane), keys strided by 4 ----
  float acc = 0.0f;
  #pragma unroll 4
  for (int kk = wave; kk < TOPK; kk += 4) {
    acc = fmaf(sc[kk], V[tk[kk] * E + h * DK + lane], acc);
  }
  red[wave][lane] = acc;
  __syncthreads();
  if (tid < DK) {
    float o = red[0][tid] + red[1][tid] + red[2][tid] + red[3][tid];
    ATT[s * E + h * DK + tid] = o * inv;
  }
}

// ---------------------------------------------------------------------------
// Launch
// ---------------------------------------------------------------------------
extern "C" void kernel_launch(void* const* d_in, const int* in_sizes, int n_in,
                              void* d_out, int out_size, void* d_ws, size_t ws_size,
                              hipStream_t stream) {
  const float* x    = (const float*)d_in[0];
  const float* Wq   = (const float*)d_in[1];
  const float* bq   = (const float*)d_in[2];
  const float* Wk   = (const float*)d_in[3];
  const float* bk   = (const float*)d_in[4];
  const float* Wv   = (const float*)d_in[5];
  const float* bv   = (const float*)d_in[6];
  const float* Wo   = (const float*)d_in[7];
  const float* bo   = (const float*)d_in[8];
  const float* iqW  = (const float*)d_in[9];
  const float* iqb  = (const float*)d_in[10];
  const float* ikW  = (const float*)d_in[11];
  const float* ikb  = (const float*)d_in[12];
  const float* wpW  = (const float*)d_in[13];
  const float* wpb  = (const float*)d_in[14];

  float* ws = (float*)d_ws;
  float* Qb  = ws;                 // S*E
  float* Kb  = Qb + S * E;         // S*E
  float* Vb  = Kb + S * E;         // S*E
  float* QI  = Vb + S * E;         // S*E
  float* KI  = QI + S * E;         // S*DK
  float* WI  = KI + S * DK;        // S*H
  float* ISC = WI + S * H;         // S*S
  int*   TK  = (int*)(ISC + S * S);     // S*TOPK ints
  float* ATT = (float*)(TK + S * TOPK); // S*E

  SegTable tab;
  tab.W[0] = Wq;  tab.b[0] = bq;  tab.out[0] = Qb;
  tab.W[1] = Wk;  tab.b[1] = bk;  tab.out[1] = Kb;
  tab.W[2] = Wv;  tab.b[2] = bv;  tab.out[2] = Vb;
  tab.W[3] = iqW; tab.b[3] = iqb; tab.out[3] = QI;
  tab.W[4] = ikW; tab.b[4] = ikb; tab.out[4] = KI;
  tab.W[5] = wpW; tab.b[5] = wpb; tab.out[5] = WI;

  // all 6 projections: 34 n-tiles x 24 m-tiles = 816 blocks
  fused_proj_kernel<<<dim3(34, S / 32), dim3(256), 0, stream>>>(x, tab);
  // indexer scores: 12 t-tiles x 24 s-tiles = 288 blocks
  indexer_kernel<<<dim3(S / 64, S / 32), dim3(256), 0, stream>>>(QI, KI, WI, ISC);
  // top-k per row
  topk_kernel<<<dim3(S), dim3(512), 0, stream>>>(ISC, TK);
  // sparse attention: (8 heads, 768 tokens) = 6144 blocks
  attn_kernel<<<dim3(H, S), dim3(256), 0, stream>>>(Qb, Kb, Vb, TK, ATT);
  // output projection: 8 x 24 = 192 blocks
  gemm_bias32<<<dim3(E / TN, S / 32), dim3(256), 0, stream>>>(ATT, Wo, bo, (float*)d_out, E, E);
}

// Round 4
// 314.258 us; speedup vs baseline: 1.3433x; 1.3433x over previous
//
#include <hip/hip_runtime.h>
#include <hip/hip_bf16.h>
#include <math.h>

// Problem constants
#define S 768
#define E 512
#define H 8
#define DK 64
#define TOPK 384

#define TN 64
#define BK 16

// ---------------------------------------------------------------------------
// Templated fp32 GEMM tile (bias added), float4 LDS reads.
// ---------------------------------------------------------------------------
template <int TMT>
__device__ __forceinline__ void gemm_tile(
    const float* __restrict__ A, const float* __restrict__ W,
    const float* __restrict__ bias, float* __restrict__ C,
    int N, int K, int m0, int n0) {
  constexpr int RM = TMT / 16;                 // rows per thread
  __shared__ __align__(16) float As[BK][TMT + 8];   // [k][m]
  __shared__ __align__(16) float Ws[BK][68];        // [k][n]
  const int tid = threadIdx.x;
  const int tm = (tid >> 4) * RM;
  const int tn = (tid & 15) << 2;
  const int wr = tid >> 4;
  const int wc = tid & 15;
  const bool fullN = (n0 + TN <= N);
  float acc[RM][4] = {};
  for (int k0 = 0; k0 < K; k0 += BK) {
    if (tid < TMT * 4) {
      int am = tid >> 2, ac = tid & 3;
      float4 av = *(const float4*)(A + (m0 + am) * K + k0 + ac * 4);
      As[ac * 4 + 0][am] = av.x;
      As[ac * 4 + 1][am] = av.y;
      As[ac * 4 + 2][am] = av.z;
      As[ac * 4 + 3][am] = av.w;
    }
    if (fullN) {
      *(float4*)&Ws[wr][wc * 4] = *(const float4*)(W + (k0 + wr) * N + n0 + wc * 4);
    } else {
      #pragma unroll
      for (int j = 0; j < 4; ++j) {
        int n = n0 + wc * 4 + j;
        Ws[wr][wc * 4 + j] = (n < N) ? W[(k0 + wr) * N + n] : 0.0f;
      }
    }
    __syncthreads();
    #pragma unroll
    for (int k = 0; k < BK; ++k) {
      float ar[RM];
      #pragma unroll
      for (int x = 0; x < RM; ++x) ar[x] = As[k][tm + x];
      float4 w4 = *(const float4*)&Ws[k][tn];
      float wv[4] = {w4.x, w4.y, w4.z, w4.w};
      #pragma unroll
      for (int x = 0; x < RM; ++x)
        #pragma unroll
        for (int y = 0; y < 4; ++y)
          acc[x][y] = fmaf(ar[x], wv[y], acc[x][y]);
    }
    __syncthreads();
  }
  #pragma unroll
  for (int x = 0; x < RM; ++x) {
    int m = m0 + tm + x;
    #pragma unroll
    for (int y = 0; y < 4; ++y) {
      int n = n0 + tn + y;
      if (n < N) C[m * N + n] = acc[x][y] + bias[n];
    }
  }
}

// ---------------------------------------------------------------------------
// Fused projections, TM=32.
// ---------------------------------------------------------------------------
struct SegTable {
  const float* W[6];
  const float* b[6];
  float*       out[6];
};

__global__ __launch_bounds__(256) void fused_proj_kernel(
    const float* __restrict__ A, SegTable tab) {
  int bx = blockIdx.x;
  int seg, nt;
  if (bx < 32) { seg = bx >> 3; nt = bx & 7; }
  else         { seg = 4 + (bx - 32); nt = 0; }
  const int N = (seg < 4) ? 512 : (seg == 4 ? 64 : 8);
  gemm_tile<32>(A, tab.W[seg], tab.b[seg], tab.out[seg], N, E,
                blockIdx.y * 32, nt * TN);
}

__global__ __launch_bounds__(256) void gemm_bias32(
    const float* __restrict__ A, const float* __restrict__ W,
    const float* __restrict__ bias, float* __restrict__ C, int N, int K) {
  gemm_tile<32>(A, W, bias, C, N, K, blockIdx.y * 32, blockIdx.x * TN);
}

// ---------------------------------------------------------------------------
// Indexer: ISC[s][t] = sum_h relu( dot64(QI[s,h*64:], KI[t,:]) ) * WI[s][h]
// ---------------------------------------------------------------------------
__global__ __launch_bounds__(256) void indexer_kernel(
    const float* __restrict__ QI, const float* __restrict__ KI,
    const float* __restrict__ WI, float* __restrict__ ISC) {
  __shared__ __align__(16) float ks[DK][68];   // [d][t]
  __shared__ __align__(16) float qs[DK][36];   // [d][s]
  const int tid = threadIdx.x;
  const int s0 = blockIdx.y * 32;
  const int t0 = blockIdx.x * 64;
  {
    int t = tid >> 2;
    int cb = tid & 3;
    #pragma unroll
    for (int cc = 0; cc < 4; ++cc) {
      int c = cb + cc * 4;
      float4 kv = *(const float4*)(KI + (t0 + t) * DK + c * 4);
      ks[c * 4 + 0][t] = kv.x;
      ks[c * 4 + 1][t] = kv.y;
      ks[c * 4 + 2][t] = kv.z;
      ks[c * 4 + 3][t] = kv.w;
    }
  }
  const int si = (tid >> 4) * 2;
  const int ti = (tid & 15) * 4;
  float acc[2][4] = {};
  for (int h = 0; h < H; ++h) {
    __syncthreads();
    #pragma unroll
    for (int r = 0; r < 2; ++r) {
      int idx = tid + r * 256;
      int s = idx >> 4;
      int c = idx & 15;
      float4 qv = *(const float4*)(QI + (s0 + s) * E + h * DK + c * 4);
      qs[c * 4 + 0][s] = qv.x;
      qs[c * 4 + 1][s] = qv.y;
      qs[c * 4 + 2][s] = qv.z;
      qs[c * 4 + 3][s] = qv.w;
    }
    __syncthreads();
    float dot[2][4] = {};
    #pragma unroll
    for (int d = 0; d < DK; ++d) {
      float4 kv = *(const float4*)&ks[d][ti];
      float kr[4] = {kv.x, kv.y, kv.z, kv.w};
      float q0 = qs[d][si];
      float q1 = qs[d][si + 1];
      #pragma unroll
      for (int j = 0; j < 4; ++j) {
        dot[0][j] = fmaf(q0, kr[j], dot[0][j]);
        dot[1][j] = fmaf(q1, kr[j], dot[1][j]);
      }
    }
    float w0 = WI[(s0 + si) * H + h];
    float w1 = WI[(s0 + si + 1) * H + h];
    #pragma unroll
    for (int j = 0; j < 4; ++j) {
      acc[0][j] += fmaxf(dot[0][j], 0.0f) * w0;
      acc[1][j] += fmaxf(dot[1][j], 0.0f) * w1;
    }
  }
  #pragma unroll
  for (int i = 0; i < 2; ++i) {
    float4 o = {acc[i][0], acc[i][1], acc[i][2], acc[i][3]};
    *(float4*)(ISC + (s0 + si + i) * S + t0 + ti) = o;
  }
}

// ---------------------------------------------------------------------------
// Top-k via bitonic sort (desc value, asc index ties == jax.lax.top_k).
// ---------------------------------------------------------------------------
__global__ __launch_bounds__(512) void topk_kernel(
    const float* __restrict__ ISC, int* __restrict__ TK) {
  __shared__ float v[1024];
  __shared__ int   ix[1024];
  const int s = blockIdx.x;
  const int tid = threadIdx.x;
  for (int i = tid; i < 1024; i += 512) {
    v[i] = (i < S) ? ISC[s * S + i] : -3.402823466e38f;
    ix[i] = i;
  }
  __syncthreads();
  for (int k = 2; k <= 1024; k <<= 1) {
    for (int j = k >> 1; j > 0; j >>= 1) {
      #pragma unroll
      for (int t = tid; t < 1024; t += 512) {
        int l = t ^ j;
        if (l > t) {
          float vt = v[t], vl = v[l];
          int it = ix[t], il = ix[l];
          bool l_before_t = (vl > vt) || (vl == vt && il < it);
          bool up = ((t & k) == 0);
          if (up ? l_before_t : !l_before_t) {
            v[t] = vl; v[l] = vt;
            ix[t] = il; ix[l] = it;
          }
        }
      }
      __syncthreads();
    }
  }
  if (tid < TOPK) TK[s * TOPK + tid] = ix[tid];
}

// ---------------------------------------------------------------------------
// Sparse attention: one block per (head, token), 256 threads.
// Scores: THREAD-per-key (full-lane-efficiency 64-dim dots, float4 gathers).
// V: wave g takes keys g::4, lane = dim (coalesced 256B rows), LDS reduce.
// ---------------------------------------------------------------------------
__global__ __launch_bounds__(256) void attn_kernel(
    const float* __restrict__ Q, const float* __restrict__ K,
    const float* __restrict__ V, const int* __restrict__ TK,
    float* __restrict__ ATT) {
  __shared__ float sc[TOPK];
  __shared__ int   tk[TOPK];
  __shared__ __align__(16) float qsh[DK];
  __shared__ float red[4][DK];
  __shared__ float wred[4];
  const int h = blockIdx.x;
  const int s = blockIdx.y;
  const int tid = threadIdx.x;
  const int lane = tid & 63;
  const int wave = tid >> 6;

  for (int i = tid; i < TOPK; i += 256) tk[i] = TK[s * TOPK + i];
  if (tid < DK) qsh[tid] = Q[s * E + h * DK + tid];
  __syncthreads();

  // ---- scores: one thread per key (keys tid and tid+256) ----
  for (int kk = tid; kk < TOPK; kk += 256) {
    int t = tk[kk];
    const float4* Kt = (const float4*)(K + t * E + h * DK);
    const float4* Qh = (const float4*)qsh;
    float dot = 0.0f;
    #pragma unroll
    for (int d4 = 0; d4 < DK / 4; ++d4) {
      float4 kv = Kt[d4];
      float4 qv = Qh[d4];      // LDS broadcast
      dot += kv.x * qv.x + kv.y * qv.y + kv.z * qv.z + kv.w * qv.w;
    }
    sc[kk] = dot * 0.125f;
  }
  __syncthreads();

  // ---- softmax over sc[0..383] ----
  float m;
  {
    float a = sc[tid];
    float b = (tid < TOPK - 256) ? sc[tid + 256] : -3.402823466e38f;
    m = fmaxf(a, b);
  }
  #pragma unroll
  for (int off = 32; off > 0; off >>= 1) m = fmaxf(m, __shfl_xor(m, off));
  if (lane == 0) wred[wave] = m;
  __syncthreads();
  m = fmaxf(fmaxf(wred[0], wred[1]), fmaxf(wred[2], wred[3]));

  float psum = 0.0f;
  {
    float e = expf(sc[tid] - m);
    sc[tid] = e;
    psum = e;
    if (tid < TOPK - 256) {
      float e2 = expf(sc[tid + 256] - m);
      sc[tid + 256] = e2;
      psum += e2;
    }
  }
  #pragma unroll
  for (int off = 32; off > 0; off >>= 1) psum += __shfl_xor(psum, off);
  __syncthreads();   // sc[] exp values visible to all
  if (lane == 0) wred[wave] = psum;
  __syncthreads();
  const float inv = 1.0f / (wred[0] + wred[1] + wred[2] + wred[3]);

  // ---- V accumulation: wave g, lane = dim, keys strided by 4 ----
  float acc = 0.0f;
  #pragma unroll 4
  for (int kk = wave; kk < TOPK; kk += 4) {
    acc = fmaf(sc[kk], V[tk[kk] * E + h * DK + lane], acc);
  }
  red[wave][lane] = acc;
  __syncthreads();
  if (tid < DK) {
    float o = red[0][tid] + red[1][tid] + red[2][tid] + red[3][tid];
    ATT[s * E + h * DK + tid] = o * inv;
  }
}

// ---------------------------------------------------------------------------
// Launch
// ---------------------------------------------------------------------------
extern "C" void kernel_launch(void* const* d_in, const int* in_sizes, int n_in,
                              void* d_out, int out_size, void* d_ws, size_t ws_size,
                              hipStream_t stream) {
  const float* x    = (const float*)d_in[0];
  const float* Wq   = (const float*)d_in[1];
  const float* bq   = (const float*)d_in[2];
  const float* Wk   = (const float*)d_in[3];
  const float* bk   = (const float*)d_in[4];
  const float* Wv   = (const float*)d_in[5];
  const float* bv   = (const float*)d_in[6];
  const float* Wo   = (const float*)d_in[7];
  const float* bo   = (const float*)d_in[8];
  const float* iqW  = (const float*)d_in[9];
  const float* iqb  = (const float*)d_in[10];
  const float* ikW  = (const float*)d_in[11];
  const float* ikb  = (const float*)d_in[12];
  const float* wpW  = (const float*)d_in[13];
  const float* wpb  = (const float*)d_in[14];

  float* ws = (float*)d_ws;
  float* Qb  = ws;                 // S*E
  float* Kb  = Qb + S * E;         // S*E
  float* Vb  = Kb + S * E;         // S*E
  float* QI  = Vb + S * E;         // S*E
  float* KI  = QI + S * E;         // S*DK
  float* WI  = KI + S * DK;        // S*H
  float* ISC = WI + S * H;         // S*S
  int*   TK  = (int*)(ISC + S * S);     // S*TOPK ints
  float* ATT = (float*)(TK + S * TOPK); // S*E

  SegTable tab;
  tab.W[0] = Wq;  tab.b[0] = bq;  tab.out[0] = Qb;
  tab.W[1] = Wk;  tab.b[1] = bk;  tab.out[1] = Kb;
  tab.W[2] = Wv;  tab.b[2] = bv;  tab.out[2] = Vb;
  tab.W[3] = iqW; tab.b[3] = iqb; tab.out[3] = QI;
  tab.W[4] = ikW; tab.b[4] = ikb; tab.out[4] = KI;
  tab.W[5] = wpW; tab.b[5] = wpb; tab.out[5] = WI;

  // all 6 projections: 34 n-tiles x 24 m-tiles = 816 blocks
  fused_proj_kernel<<<dim3(34, S / 32), dim3(256), 0, stream>>>(x, tab);
  // indexer scores: 12 t-tiles x 24 s-tiles = 288 blocks
  indexer_kernel<<<dim3(S / 64, S / 32), dim3(256), 0, stream>>>(QI, KI, WI, ISC);
  // top-k per row
  topk_kernel<<<dim3(S), dim3(512), 0, stream>>>(ISC, TK);
  // sparse attention: (8 heads, 768 tokens) = 6144 blocks
  attn_kernel<<<dim3(H, S), dim3(256), 0, stream>>>(Qb, Kb, Vb, TK, ATT);
  // output projection: 8 x 24 = 192 blocks
  gemm_bias32<<<dim3(E / TN, S / 32), dim3(256), 0, stream>>>(ATT, Wo, bo, (float*)d_out, E, E);
}

// Round 5
// 301.534 us; speedup vs baseline: 1.4000x; 1.0422x over previous
//
#include <hip/hip_runtime.h>
#include <hip/hip_bf16.h>
#include <math.h>

// Problem constants
#define S 768
#define E 512
#define H 8
#define DK 64
#define TOPK 384

#define TM 64
#define TN 64
#define BK 16

// ---------------------------------------------------------------------------
// Fused projections: 64x64 tile, 4x4 per thread, float4 LDS reads (16 FMA :
// 2 ds_read_b128 per k-step). Custom epilogue: K/V segs stored HEAD-MAJOR
// [h][s][d] for the attention gather; others row-major.
// ---------------------------------------------------------------------------
struct SegTable {
  const float* W[6];
  const float* b[6];
  float*       out[6];
};

__global__ __launch_bounds__(256) void fused_proj_kernel(
    const float* __restrict__ A, SegTable tab) {
  __shared__ __align__(16) float As[BK][TM + 8];   // [k][m]
  __shared__ __align__(16) float Ws[BK][TN + 4];   // [k][n]
  const int bx = blockIdx.x;
  int seg, nt;
  if (bx < 32) { seg = bx >> 3; nt = bx & 7; }
  else         { seg = 4 + (bx - 32); nt = 0; }
  const int N = (seg < 4) ? 512 : (seg == 4 ? 64 : 8);
  const float* __restrict__ W = tab.W[seg];
  const float* __restrict__ bias = tab.b[seg];
  float* __restrict__ C = tab.out[seg];
  const int m0 = blockIdx.y * TM;
  const int n0 = nt * TN;

  const int tid = threadIdx.x;
  const int tm = (tid >> 4) << 2;
  const int tn = (tid & 15) << 2;
  const int am = tid >> 2;            // A row
  const int ac = tid & 3;             // float4 col index along k
  const int wr = tid >> 4;            // W k-row
  const int wc = tid & 15;            // float4 index along n
  const bool fullN = (N >= TN);
  float acc[4][4] = {};
  for (int k0 = 0; k0 < E; k0 += BK) {
    float4 av = *(const float4*)(A + (m0 + am) * E + k0 + ac * 4);
    As[ac * 4 + 0][am] = av.x;
    As[ac * 4 + 1][am] = av.y;
    As[ac * 4 + 2][am] = av.z;
    As[ac * 4 + 3][am] = av.w;
    if (fullN) {
      *(float4*)&Ws[wr][wc * 4] = *(const float4*)(W + (k0 + wr) * N + n0 + wc * 4);
    } else {
      #pragma unroll
      for (int j = 0; j < 4; ++j) {
        int n = wc * 4 + j;
        Ws[wr][wc * 4 + j] = (n < N) ? W[(k0 + wr) * N + n] : 0.0f;
      }
    }
    __syncthreads();
    #pragma unroll
    for (int k = 0; k < BK; ++k) {
      float4 a4 = *(const float4*)&As[k][tm];
      float4 w4 = *(const float4*)&Ws[k][tn];
      float ar[4] = {a4.x, a4.y, a4.z, a4.w};
      float wv[4] = {w4.x, w4.y, w4.z, w4.w};
      #pragma unroll
      for (int x = 0; x < 4; ++x)
        #pragma unroll
        for (int y = 0; y < 4; ++y)
          acc[x][y] = fmaf(ar[x], wv[y], acc[x][y]);
    }
    __syncthreads();
  }
  // epilogue
  if (seg == 1 || seg == 2) {
    // head-major: C[h*S*64 + m*64 + d], h = n0/64, d = tn..tn+3
    float* Ch = C + (n0 >> 6) * (S * DK);
    float4 b4 = *(const float4*)(bias + n0 + tn);
    #pragma unroll
    for (int x = 0; x < 4; ++x) {
      int m = m0 + tm + x;
      float4 o = {acc[x][0] + b4.x, acc[x][1] + b4.y,
                  acc[x][2] + b4.z, acc[x][3] + b4.w};
      *(float4*)(Ch + m * DK + tn) = o;
    }
  } else if (seg != 5) {
    // row-major, N = 512 (segs 0,3) or 64 (seg 4)
    float4 b4 = *(const float4*)(bias + n0 + tn);
    #pragma unroll
    for (int x = 0; x < 4; ++x) {
      int m = m0 + tm + x;
      float4 o = {acc[x][0] + b4.x, acc[x][1] + b4.y,
                  acc[x][2] + b4.z, acc[x][3] + b4.w};
      *(float4*)(C + m * N + n0 + tn) = o;
    }
  } else {
    // seg 5: N = 8, guarded scalar stores
    #pragma unroll
    for (int x = 0; x < 4; ++x) {
      int m = m0 + tm + x;
      #pragma unroll
      for (int y = 0; y < 4; ++y) {
        int n = tn + y;
        if (n < 8) C[m * 8 + n] = acc[x][y] + bias[n];
      }
    }
  }
}

// ---------------------------------------------------------------------------
// Plain 64x64 GEMM + bias (row-major out) for the output projection.
// ---------------------------------------------------------------------------
__global__ __launch_bounds__(256) void gemm_bias64(
    const float* __restrict__ A, const float* __restrict__ W,
    const float* __restrict__ bias, float* __restrict__ C, int N, int K) {
  __shared__ __align__(16) float As[BK][TM + 8];
  __shared__ __align__(16) float Ws[BK][TN + 4];
  const int m0 = blockIdx.y * TM;
  const int n0 = blockIdx.x * TN;
  const int tid = threadIdx.x;
  const int tm = (tid >> 4) << 2;
  const int tn = (tid & 15) << 2;
  const int am = tid >> 2;
  const int ac = tid & 3;
  const int wr = tid >> 4;
  const int wc = tid & 15;
  float acc[4][4] = {};
  for (int k0 = 0; k0 < K; k0 += BK) {
    float4 av = *(const float4*)(A + (m0 + am) * K + k0 + ac * 4);
    As[ac * 4 + 0][am] = av.x;
    As[ac * 4 + 1][am] = av.y;
    As[ac * 4 + 2][am] = av.z;
    As[ac * 4 + 3][am] = av.w;
    *(float4*)&Ws[wr][wc * 4] = *(const float4*)(W + (k0 + wr) * N + n0 + wc * 4);
    __syncthreads();
    #pragma unroll
    for (int k = 0; k < BK; ++k) {
      float4 a4 = *(const float4*)&As[k][tm];
      float4 w4 = *(const float4*)&Ws[k][tn];
      float ar[4] = {a4.x, a4.y, a4.z, a4.w};
      float wv[4] = {w4.x, w4.y, w4.z, w4.w};
      #pragma unroll
      for (int x = 0; x < 4; ++x)
        #pragma unroll
        for (int y = 0; y < 4; ++y)
          acc[x][y] = fmaf(ar[x], wv[y], acc[x][y]);
    }
    __syncthreads();
  }
  float4 b4 = *(const float4*)(bias + n0 + tn);
  #pragma unroll
  for (int x = 0; x < 4; ++x) {
    int m = m0 + tm + x;
    float4 o = {acc[x][0] + b4.x, acc[x][1] + b4.y,
                acc[x][2] + b4.z, acc[x][3] + b4.w};
    *(float4*)(C + m * N + n0 + tn) = o;
  }
}

// ---------------------------------------------------------------------------
// Indexer: ISC[s][t] = sum_h relu( dot64(QI[s,h*64:], KI[t,:]) ) * WI[s][h]
// (unchanged from round 4 — keeps the top-k selection bit-identical)
// ---------------------------------------------------------------------------
__global__ __launch_bounds__(256) void indexer_kernel(
    const float* __restrict__ QI, const float* __restrict__ KI,
    const float* __restrict__ WI, float* __restrict__ ISC) {
  __shared__ __align__(16) float ks[DK][68];   // [d][t]
  __shared__ __align__(16) float qs[DK][36];   // [d][s]
  const int tid = threadIdx.x;
  const int s0 = blockIdx.y * 32;
  const int t0 = blockIdx.x * 64;
  {
    int t = tid >> 2;
    int cb = tid & 3;
    #pragma unroll
    for (int cc = 0; cc < 4; ++cc) {
      int c = cb + cc * 4;
      float4 kv = *(const float4*)(KI + (t0 + t) * DK + c * 4);
      ks[c * 4 + 0][t] = kv.x;
      ks[c * 4 + 1][t] = kv.y;
      ks[c * 4 + 2][t] = kv.z;
      ks[c * 4 + 3][t] = kv.w;
    }
  }
  const int si = (tid >> 4) * 2;
  const int ti = (tid & 15) * 4;
  float acc[2][4] = {};
  for (int h = 0; h < H; ++h) {
    __syncthreads();
    #pragma unroll
    for (int r = 0; r < 2; ++r) {
      int idx = tid + r * 256;
      int s = idx >> 4;
      int c = idx & 15;
      float4 qv = *(const float4*)(QI + (s0 + s) * E + h * DK + c * 4);
      qs[c * 4 + 0][s] = qv.x;
      qs[c * 4 + 1][s] = qv.y;
      qs[c * 4 + 2][s] = qv.z;
      qs[c * 4 + 3][s] = qv.w;
    }
    __syncthreads();
    float dot[2][4] = {};
    #pragma unroll
    for (int d = 0; d < DK; ++d) {
      float4 kv = *(const float4*)&ks[d][ti];
      float kr[4] = {kv.x, kv.y, kv.z, kv.w};
      float q0 = qs[d][si];
      float q1 = qs[d][si + 1];
      #pragma unroll
      for (int j = 0; j < 4; ++j) {
        dot[0][j] = fmaf(q0, kr[j], dot[0][j]);
        dot[1][j] = fmaf(q1, kr[j], dot[1][j]);
      }
    }
    float w0 = WI[(s0 + si) * H + h];
    float w1 = WI[(s0 + si + 1) * H + h];
    #pragma unroll
    for (int j = 0; j < 4; ++j) {
      acc[0][j] += fmaxf(dot[0][j], 0.0f) * w0;
      acc[1][j] += fmaxf(dot[1][j], 0.0f) * w1;
    }
  }
  #pragma unroll
  for (int i = 0; i < 2; ++i) {
    float4 o = {acc[i][0], acc[i][1], acc[i][2], acc[i][3]};
    *(float4*)(ISC + (s0 + si + i) * S + t0 + ti) = o;
  }
}

// ---------------------------------------------------------------------------
// Top-k via bitonic sort (desc value, asc index ties == jax.lax.top_k).
// ---------------------------------------------------------------------------
__global__ __launch_bounds__(512) void topk_kernel(
    const float* __restrict__ ISC, int* __restrict__ TK) {
  __shared__ float v[1024];
  __shared__ int   ix[1024];
  const int s = blockIdx.x;
  const int tid = threadIdx.x;
  for (int i = tid; i < 1024; i += 512) {
    v[i] = (i < S) ? ISC[s * S + i] : -3.402823466e38f;
    ix[i] = i;
  }
  __syncthreads();
  for (int k = 2; k <= 1024; k <<= 1) {
    for (int j = k >> 1; j > 0; j >>= 1) {
      #pragma unroll
      for (int t = tid; t < 1024; t += 512) {
        int l = t ^ j;
        if (l > t) {
          float vt = v[t], vl = v[l];
          int it = ix[t], il = ix[l];
          bool l_before_t = (vl > vt) || (vl == vt && il < it);
          bool up = ((t & k) == 0);
          if (up ? l_before_t : !l_before_t) {
            v[t] = vl; v[l] = vt;
            ix[t] = il; ix[l] = it;
          }
        }
      }
      __syncthreads();
    }
  }
  if (tid < TOPK) TK[s * TOPK + tid] = ix[tid];
}

// ---------------------------------------------------------------------------
// Sparse attention: block = (s fast, h slow), 512 threads (8 waves).
// K/V are HEAD-MAJOR [h][t][64] -> per-head 196 KB hot slab, L2-friendly.
// Scores: one thread per key (tid<384), balanced. V: 8 waves, lane=dim,
// 2 independent FMA chains, LDS reduce over 8 partials.
// ---------------------------------------------------------------------------
__global__ __launch_bounds__(512) void attn_kernel(
    const float* __restrict__ Q, const float* __restrict__ Khm,
    const float* __restrict__ Vhm, const int* __restrict__ TK,
    float* __restrict__ ATT) {
  __shared__ float sc[TOPK];
  __shared__ int   tk[TOPK];
  __shared__ __align__(16) float qsh[DK];
  __shared__ float red[8][DK];
  __shared__ float wred[8];
  const int s = blockIdx.x;
  const int h = blockIdx.y;
  const int tid = threadIdx.x;
  const int lane = tid & 63;
  const int wave = tid >> 6;

  if (tid < TOPK) tk[tid] = TK[s * TOPK + tid];
  if (tid < DK) qsh[tid] = Q[s * E + h * DK + tid];
  __syncthreads();

  const float* __restrict__ Kh = Khm + h * (S * DK);
  const float* __restrict__ Vh = Vhm + h * (S * DK);

  // ---- scores: one thread per key ----
  if (tid < TOPK) {
    int t = tk[tid];
    const float4* Kt = (const float4*)(Kh + t * DK);
    const float4* Qh = (const float4*)qsh;
    float dot = 0.0f;
    #pragma unroll
    for (int d4 = 0; d4 < DK / 4; ++d4) {
      float4 kv = Kt[d4];
      float4 qv = Qh[d4];
      dot += kv.x * qv.x + kv.y * qv.y + kv.z * qv.z + kv.w * qv.w;
    }
    sc[tid] = dot * 0.125f;
  }
  __syncthreads();

  // ---- softmax ----
  float m = (tid < TOPK) ? sc[tid] : -3.402823466e38f;
  #pragma unroll
  for (int off = 32; off > 0; off >>= 1) m = fmaxf(m, __shfl_xor(m, off));
  if (lane == 0) wred[wave] = m;
  __syncthreads();
  m = wred[0];
  #pragma unroll
  for (int w = 1; w < 8; ++w) m = fmaxf(m, wred[w]);

  float psum = 0.0f;
  if (tid < TOPK) {
    float e = expf(sc[tid] - m);
    sc[tid] = e;
    psum = e;
  }
  #pragma unroll
  for (int off = 32; off > 0; off >>= 1) psum += __shfl_xor(psum, off);
  __syncthreads();   // everyone done reading wred (max) and writing sc
  if (lane == 0) wred[wave] = psum;
  __syncthreads();
  float tot = wred[0];
  #pragma unroll
  for (int w = 1; w < 8; ++w) tot += wred[w];
  const float inv = 1.0f / tot;

  // ---- V accumulation: wave g, lane = dim, keys g::8, 2 chains ----
  float a0 = 0.0f, a1 = 0.0f;
  #pragma unroll 4
  for (int kk = wave; kk < TOPK; kk += 16) {
    a0 = fmaf(sc[kk],     Vh[tk[kk]     * DK + lane], a0);
    a1 = fmaf(sc[kk + 8], Vh[tk[kk + 8] * DK + lane], a1);
  }
  red[wave][lane] = a0 + a1;
  __syncthreads();
  if (tid < DK) {
    float o = 0.0f;
    #pragma unroll
    for (int w = 0; w < 8; ++w) o += red[w][tid];
    ATT[s * E + h * DK + tid] = o * inv;
  }
}

// ---------------------------------------------------------------------------
// Launch
// ---------------------------------------------------------------------------
extern "C" void kernel_launch(void* const* d_in, const int* in_sizes, int n_in,
                              void* d_out, int out_size, void* d_ws, size_t ws_size,
                              hipStream_t stream) {
  const float* x    = (const float*)d_in[0];
  const float* Wq   = (const float*)d_in[1];
  const float* bq   = (const float*)d_in[2];
  const float* Wk   = (const float*)d_in[3];
  const float* bk   = (const float*)d_in[4];
  const float* Wv   = (const float*)d_in[5];
  const float* bv   = (const float*)d_in[6];
  const float* Wo   = (const float*)d_in[7];
  const float* bo   = (const float*)d_in[8];
  const float* iqW  = (const float*)d_in[9];
  const float* iqb  = (const float*)d_in[10];
  const float* ikW  = (const float*)d_in[11];
  const float* ikb  = (const float*)d_in[12];
  const float* wpW  = (const float*)d_in[13];
  const float* wpb  = (const float*)d_in[14];

  float* ws = (float*)d_ws;
  float* Qb  = ws;                 // S*E   (row-major)
  float* Khm = Qb + S * E;         // S*E   (head-major [h][t][64])
  float* Vhm = Khm + S * E;        // S*E   (head-major)
  float* QI  = Vhm + S * E;        // S*E
  float* KI  = QI + S * E;         // S*DK
  float* WI  = KI + S * DK;        // S*H
  float* ISC = WI + S * H;         // S*S
  int*   TK  = (int*)(ISC + S * S);     // S*TOPK ints
  float* ATT = (float*)(TK + S * TOPK); // S*E

  SegTable tab;
  tab.W[0] = Wq;  tab.b[0] = bq;  tab.out[0] = Qb;
  tab.W[1] = Wk;  tab.b[1] = bk;  tab.out[1] = Khm;   // head-major epilogue
  tab.W[2] = Wv;  tab.b[2] = bv;  tab.out[2] = Vhm;   // head-major epilogue
  tab.W[3] = iqW; tab.b[3] = iqb; tab.out[3] = QI;
  tab.W[4] = ikW; tab.b[4] = ikb; tab.out[4] = KI;
  tab.W[5] = wpW; tab.b[5] = wpb; tab.out[5] = WI;

  // all 6 projections: 34 n-tiles x 12 m-tiles = 408 blocks
  fused_proj_kernel<<<dim3(34, S / TM), dim3(256), 0, stream>>>(x, tab);
  // indexer scores: 12 t-tiles x 24 s-tiles = 288 blocks
  indexer_kernel<<<dim3(S / 64, S / 32), dim3(256), 0, stream>>>(QI, KI, WI, ISC);
  // top-k per row
  topk_kernel<<<dim3(S), dim3(512), 0, stream>>>(ISC, TK);
  // sparse attention: (768 s fast, 8 h slow) = 6144 blocks x 512 threads
  attn_kernel<<<dim3(S, H), dim3(512), 0, stream>>>(Qb, Khm, Vhm, TK, ATT);
  // output projection: 8 x 12 = 96 blocks
  gemm_bias64<<<dim3(E / TN, S / TM), dim3(256), 0, stream>>>(ATT, Wo, bo, (float*)d_out, E, E);
}

// Round 6
// 254.250 us; speedup vs baseline: 1.6603x; 1.1860x over previous
//
#include <hip/hip_runtime.h>
#include <hip/hip_bf16.h>
#include <math.h>

// Problem constants
#define S 768
#define E 512
#define H 8
#define DK 64
#define TOPK 384

#define TM 64
#define TN 64
#define BK 16

#define NEG_BIG (-1e30f)

// ---------------------------------------------------------------------------
// Fused projections: 64x64 tile, 4x4 per thread, float4 LDS reads.
// K/V segs stored HEAD-MAJOR [h][s][d]; others row-major.
// ---------------------------------------------------------------------------
struct SegTable {
  const float* W[6];
  const float* b[6];
  float*       out[6];
};

__global__ __launch_bounds__(256) void fused_proj_kernel(
    const float* __restrict__ A, SegTable tab) {
  __shared__ __align__(16) float As[BK][TM + 8];   // [k][m]
  __shared__ __align__(16) float Ws[BK][TN + 4];   // [k][n]
  const int bx = blockIdx.x;
  int seg, nt;
  if (bx < 32) { seg = bx >> 3; nt = bx & 7; }
  else         { seg = 4 + (bx - 32); nt = 0; }
  const int N = (seg < 4) ? 512 : (seg == 4 ? 64 : 8);
  const float* __restrict__ W = tab.W[seg];
  const float* __restrict__ bias = tab.b[seg];
  float* __restrict__ C = tab.out[seg];
  const int m0 = blockIdx.y * TM;
  const int n0 = nt * TN;

  const int tid = threadIdx.x;
  const int tm = (tid >> 4) << 2;
  const int tn = (tid & 15) << 2;
  const int am = tid >> 2;
  const int ac = tid & 3;
  const int wr = tid >> 4;
  const int wc = tid & 15;
  const bool fullN = (N >= TN);
  float acc[4][4] = {};
  for (int k0 = 0; k0 < E; k0 += BK) {
    float4 av = *(const float4*)(A + (m0 + am) * E + k0 + ac * 4);
    As[ac * 4 + 0][am] = av.x;
    As[ac * 4 + 1][am] = av.y;
    As[ac * 4 + 2][am] = av.z;
    As[ac * 4 + 3][am] = av.w;
    if (fullN) {
      *(float4*)&Ws[wr][wc * 4] = *(const float4*)(W + (k0 + wr) * N + n0 + wc * 4);
    } else {
      #pragma unroll
      for (int j = 0; j < 4; ++j) {
        int n = wc * 4 + j;
        Ws[wr][wc * 4 + j] = (n < N) ? W[(k0 + wr) * N + n] : 0.0f;
      }
    }
    __syncthreads();
    #pragma unroll
    for (int k = 0; k < BK; ++k) {
      float4 a4 = *(const float4*)&As[k][tm];
      float4 w4 = *(const float4*)&Ws[k][tn];
      float ar[4] = {a4.x, a4.y, a4.z, a4.w};
      float wv[4] = {w4.x, w4.y, w4.z, w4.w};
      #pragma unroll
      for (int x = 0; x < 4; ++x)
        #pragma unroll
        for (int y = 0; y < 4; ++y)
          acc[x][y] = fmaf(ar[x], wv[y], acc[x][y]);
    }
    __syncthreads();
  }
  if (seg == 1 || seg == 2) {
    float* Ch = C + (n0 >> 6) * (S * DK);
    float4 b4 = *(const float4*)(bias + n0 + tn);
    #pragma unroll
    for (int x = 0; x < 4; ++x) {
      int m = m0 + tm + x;
      float4 o = {acc[x][0] + b4.x, acc[x][1] + b4.y,
                  acc[x][2] + b4.z, acc[x][3] + b4.w};
      *(float4*)(Ch + m * DK + tn) = o;
    }
  } else if (seg != 5) {
    float4 b4 = *(const float4*)(bias + n0 + tn);
    #pragma unroll
    for (int x = 0; x < 4; ++x) {
      int m = m0 + tm + x;
      float4 o = {acc[x][0] + b4.x, acc[x][1] + b4.y,
                  acc[x][2] + b4.z, acc[x][3] + b4.w};
      *(float4*)(C + m * N + n0 + tn) = o;
    }
  } else {
    #pragma unroll
    for (int x = 0; x < 4; ++x) {
      int m = m0 + tm + x;
      #pragma unroll
      for (int y = 0; y < 4; ++y) {
        int n = tn + y;
        if (n < 8) C[m * 8 + n] = acc[x][y] + bias[n];
      }
    }
  }
}

// ---------------------------------------------------------------------------
// Plain 64x64 GEMM + bias for the output projection.
// ---------------------------------------------------------------------------
__global__ __launch_bounds__(256) void gemm_bias64(
    const float* __restrict__ A, const float* __restrict__ W,
    const float* __restrict__ bias, float* __restrict__ C, int N, int K) {
  __shared__ __align__(16) float As[BK][TM + 8];
  __shared__ __align__(16) float Ws[BK][TN + 4];
  const int m0 = blockIdx.y * TM;
  const int n0 = blockIdx.x * TN;
  const int tid = threadIdx.x;
  const int tm = (tid >> 4) << 2;
  const int tn = (tid & 15) << 2;
  const int am = tid >> 2;
  const int ac = tid & 3;
  const int wr = tid >> 4;
  const int wc = tid & 15;
  float acc[4][4] = {};
  for (int k0 = 0; k0 < K; k0 += BK) {
    float4 av = *(const float4*)(A + (m0 + am) * K + k0 + ac * 4);
    As[ac * 4 + 0][am] = av.x;
    As[ac * 4 + 1][am] = av.y;
    As[ac * 4 + 2][am] = av.z;
    As[ac * 4 + 3][am] = av.w;
    *(float4*)&Ws[wr][wc * 4] = *(const float4*)(W + (k0 + wr) * N + n0 + wc * 4);
    __syncthreads();
    #pragma unroll
    for (int k = 0; k < BK; ++k) {
      float4 a4 = *(const float4*)&As[k][tm];
      float4 w4 = *(const float4*)&Ws[k][tn];
      float ar[4] = {a4.x, a4.y, a4.z, a4.w};
      float wv[4] = {w4.x, w4.y, w4.z, w4.w};
      #pragma unroll
      for (int x = 0; x < 4; ++x)
        #pragma unroll
        for (int y = 0; y < 4; ++y)
          acc[x][y] = fmaf(ar[x], wv[y], acc[x][y]);
    }
    __syncthreads();
  }
  float4 b4 = *(const float4*)(bias + n0 + tn);
  #pragma unroll
  for (int x = 0; x < 4; ++x) {
    int m = m0 + tm + x;
    float4 o = {acc[x][0] + b4.x, acc[x][1] + b4.y,
                acc[x][2] + b4.z, acc[x][3] + b4.w};
    *(float4*)(C + m * N + n0 + tn) = o;
  }
}

// ---------------------------------------------------------------------------
// Indexer (unchanged — keeps top-k selection bit-identical).
// ---------------------------------------------------------------------------
__global__ __launch_bounds__(256) void indexer_kernel(
    const float* __restrict__ QI, const float* __restrict__ KI,
    const float* __restrict__ WI, float* __restrict__ ISC) {
  __shared__ __align__(16) float ks[DK][68];
  __shared__ __align__(16) float qs[DK][36];
  const int tid = threadIdx.x;
  const int s0 = blockIdx.y * 32;
  const int t0 = blockIdx.x * 64;
  {
    int t = tid >> 2;
    int cb = tid & 3;
    #pragma unroll
    for (int cc = 0; cc < 4; ++cc) {
      int c = cb + cc * 4;
      float4 kv = *(const float4*)(KI + (t0 + t) * DK + c * 4);
      ks[c * 4 + 0][t] = kv.x;
      ks[c * 4 + 1][t] = kv.y;
      ks[c * 4 + 2][t] = kv.z;
      ks[c * 4 + 3][t] = kv.w;
    }
  }
  const int si = (tid >> 4) * 2;
  const int ti = (tid & 15) * 4;
  float acc[2][4] = {};
  for (int h = 0; h < H; ++h) {
    __syncthreads();
    #pragma unroll
    for (int r = 0; r < 2; ++r) {
      int idx = tid + r * 256;
      int s = idx >> 4;
      int c = idx & 15;
      float4 qv = *(const float4*)(QI + (s0 + s) * E + h * DK + c * 4);
      qs[c * 4 + 0][s] = qv.x;
      qs[c * 4 + 1][s] = qv.y;
      qs[c * 4 + 2][s] = qv.z;
      qs[c * 4 + 3][s] = qv.w;
    }
    __syncthreads();
    float dot[2][4] = {};
    #pragma unroll
    for (int d = 0; d < DK; ++d) {
      float4 kv = *(const float4*)&ks[d][ti];
      float kr[4] = {kv.x, kv.y, kv.z, kv.w};
      float q0 = qs[d][si];
      float q1 = qs[d][si + 1];
      #pragma unroll
      for (int j = 0; j < 4; ++j) {
        dot[0][j] = fmaf(q0, kr[j], dot[0][j]);
        dot[1][j] = fmaf(q1, kr[j], dot[1][j]);
      }
    }
    float w0 = WI[(s0 + si) * H + h];
    float w1 = WI[(s0 + si + 1) * H + h];
    #pragma unroll
    for (int j = 0; j < 4; ++j) {
      acc[0][j] += fmaxf(dot[0][j], 0.0f) * w0;
      acc[1][j] += fmaxf(dot[1][j], 0.0f) * w1;
    }
  }
  #pragma unroll
  for (int i = 0; i < 2; ++i) {
    float4 o = {acc[i][0], acc[i][1], acc[i][2], acc[i][3]};
    *(float4*)(ISC + (s0 + si + i) * S + t0 + ti) = o;
  }
}

// ---------------------------------------------------------------------------
// Top-k via bitonic sort (desc value, asc index == jax.lax.top_k ties).
// Emits a 768-bit mask per row (24 uint32) instead of an index list.
// ---------------------------------------------------------------------------
__global__ __launch_bounds__(512) void topk_kernel(
    const float* __restrict__ ISC, unsigned* __restrict__ Mask) {
  __shared__ float v[1024];
  __shared__ int   ix[1024];
  __shared__ unsigned mw[24];
  const int s = blockIdx.x;
  const int tid = threadIdx.x;
  for (int i = tid; i < 1024; i += 512) {
    v[i] = (i < S) ? ISC[s * S + i] : -3.402823466e38f;
    ix[i] = i;
  }
  if (tid < 24) mw[tid] = 0u;
  __syncthreads();
  for (int k = 2; k <= 1024; k <<= 1) {
    for (int j = k >> 1; j > 0; j >>= 1) {
      #pragma unroll
      for (int t = tid; t < 1024; t += 512) {
        int l = t ^ j;
        if (l > t) {
          float vt = v[t], vl = v[l];
          int it = ix[t], il = ix[l];
          bool l_before_t = (vl > vt) || (vl == vt && il < it);
          bool up = ((t & k) == 0);
          if (up ? l_before_t : !l_before_t) {
            v[t] = vl; v[l] = vt;
            ix[t] = il; ix[l] = it;
          }
        }
      }
      __syncthreads();
    }
  }
  if (tid < TOPK) {
    int t = ix[tid];
    atomicOr(&mw[t >> 5], 1u << (t & 31));
  }
  __syncthreads();
  if (tid < 24) Mask[s * 24 + tid] = mw[tid];
}

// ---------------------------------------------------------------------------
// Dense masked scores: P[h][s][t] = mask ? dot(Q[s,h,:],K[t,h,:])*0.125 : -1e30
// 64x64 tile per block, K-dim = 64. Grid (12 t, 12 s, 8 h).
// ---------------------------------------------------------------------------
__global__ __launch_bounds__(256) void score_kernel(
    const float* __restrict__ Q,       // S x E (row-major)
    const float* __restrict__ Khm,     // [h][t][64]
    const unsigned* __restrict__ Mask, // S x 24
    float* __restrict__ P) {           // [h][s][t]
  __shared__ __align__(16) float Qs[DK][68];
  __shared__ __align__(16) float Ks[DK][68];
  const int h = blockIdx.z;
  const int s0 = blockIdx.y * 64;
  const int t0 = blockIdx.x * 64;
  const int tid = threadIdx.x;
  #pragma unroll
  for (int j = 0; j < 4; ++j) {
    int i = tid + j * 256;
    int r = i >> 4, c = i & 15;
    float4 q4 = *(const float4*)(Q + (s0 + r) * E + h * DK + c * 4);
    Qs[c * 4 + 0][r] = q4.x;
    Qs[c * 4 + 1][r] = q4.y;
    Qs[c * 4 + 2][r] = q4.z;
    Qs[c * 4 + 3][r] = q4.w;
    float4 k4 = *(const float4*)(Khm + (h * S + t0 + r) * DK + c * 4);
    Ks[c * 4 + 0][r] = k4.x;
    Ks[c * 4 + 1][r] = k4.y;
    Ks[c * 4 + 2][r] = k4.z;
    Ks[c * 4 + 3][r] = k4.w;
  }
  __syncthreads();
  const int tm = (tid >> 4) << 2;
  const int tn = (tid & 15) << 2;
  float acc[4][4] = {};
  #pragma unroll 8
  for (int d = 0; d < DK; ++d) {
    float4 a4 = *(const float4*)&Qs[d][tm];
    float4 b4 = *(const float4*)&Ks[d][tn];
    float ar[4] = {a4.x, a4.y, a4.z, a4.w};
    float br[4] = {b4.x, b4.y, b4.z, b4.w};
    #pragma unroll
    for (int x = 0; x < 4; ++x)
      #pragma unroll
      for (int y = 0; y < 4; ++y)
        acc[x][y] = fmaf(ar[x], br[y], acc[x][y]);
  }
  const int wsh = tn & 31;
  #pragma unroll
  for (int x = 0; x < 4; ++x) {
    int s = s0 + tm + x;
    unsigned w = Mask[s * 24 + ((t0 + tn) >> 5)];
    float4 o;
    o.x = ((w >> (wsh + 0)) & 1u) ? acc[x][0] * 0.125f : NEG_BIG;
    o.y = ((w >> (wsh + 1)) & 1u) ? acc[x][1] * 0.125f : NEG_BIG;
    o.z = ((w >> (wsh + 2)) & 1u) ? acc[x][2] * 0.125f : NEG_BIG;
    o.w = ((w >> (wsh + 3)) & 1u) ? acc[x][3] * 0.125f : NEG_BIG;
    *(float4*)(P + ((size_t)h * S + s) * S + t0 + tn) = o;
  }
}

// ---------------------------------------------------------------------------
// Row softmax stats: Mrow = max, Inv = 1/sum(exp(sc-max)). Wave per row.
// ---------------------------------------------------------------------------
__global__ __launch_bounds__(256) void stats_kernel(
    const float* __restrict__ P, float* __restrict__ Mrow,
    float* __restrict__ Inv) {
  const int row = blockIdx.x * 4 + (threadIdx.x >> 6);   // h*S + s
  const int lane = threadIdx.x & 63;
  const float* p = P + (size_t)row * S;
  float v[12];
  float m = -3.402823466e38f;
  #pragma unroll
  for (int j = 0; j < 12; ++j) {
    v[j] = p[lane + 64 * j];
    m = fmaxf(m, v[j]);
  }
  #pragma unroll
  for (int off = 32; off > 0; off >>= 1) m = fmaxf(m, __shfl_xor(m, off));
  float l = 0.0f;
  #pragma unroll
  for (int j = 0; j < 12; ++j) l += expf(v[j] - m);
  #pragma unroll
  for (int off = 32; off > 0; off >>= 1) l += __shfl_xor(l, off);
  if (lane == 0) {
    Mrow[row] = m;
    Inv[row] = 1.0f / l;
  }
}

// ---------------------------------------------------------------------------
// PV GEMM with K-split=4: Opart[ks][s][h*64+d] = sum_{t in chunk} exp(P-m)*V.
// Tile 32s x 64d, chunk = 192 t. Grid (4 ks, 24 s, 8 h).
// ---------------------------------------------------------------------------
__global__ __launch_bounds__(256) void pv_kernel(
    const float* __restrict__ P, const float* __restrict__ Vhm,
    const float* __restrict__ Mrow, float* __restrict__ Opart) {
  __shared__ __align__(16) float Ps[16][36];   // [t][s] exp-applied
  __shared__ __align__(16) float Vs[16][68];   // [t][d]
  __shared__ float msh[32];
  const int ks = blockIdx.x;
  const int s0 = blockIdx.y * 32;
  const int h  = blockIdx.z;
  const int tid = threadIdx.x;
  if (tid < 32) msh[tid] = Mrow[h * S + s0 + tid];
  __syncthreads();
  const int si = (tid >> 4) << 1;   // 0..30
  const int td = (tid & 15) << 2;   // 0..60
  const size_t Pbase = ((size_t)h * S + s0) * S;
  float acc0[4] = {}, acc1[4] = {};
  for (int kt = 0; kt < 12; ++kt) {
    const int t0 = ks * 192 + kt * 16;
    if (tid < 128) {
      int r = tid >> 2, c = tid & 3;
      float4 p4 = *(const float4*)(P + Pbase + (size_t)r * S + t0 + c * 4);
      float mr = msh[r];
      Ps[c * 4 + 0][r] = expf(p4.x - mr);
      Ps[c * 4 + 1][r] = expf(p4.y - mr);
      Ps[c * 4 + 2][r] = expf(p4.z - mr);
      Ps[c * 4 + 3][r] = expf(p4.w - mr);
    }
    {
      int r = tid >> 4, c = tid & 15;
      float4 v4 = *(const float4*)(Vhm + ((size_t)h * S + t0 + r) * DK + c * 4);
      *(float4*)&Vs[r][c * 4] = v4;
    }
    __syncthreads();
    #pragma unroll
    for (int t = 0; t < 16; ++t) {
      float p0 = Ps[t][si];
      float p1 = Ps[t][si + 1];
      float4 v4 = *(const float4*)&Vs[t][td];
      acc0[0] = fmaf(p0, v4.x, acc0[0]);
      acc0[1] = fmaf(p0, v4.y, acc0[1]);
      acc0[2] = fmaf(p0, v4.z, acc0[2]);
      acc0[3] = fmaf(p0, v4.w, acc0[3]);
      acc1[0] = fmaf(p1, v4.x, acc1[0]);
      acc1[1] = fmaf(p1, v4.y, acc1[1]);
      acc1[2] = fmaf(p1, v4.z, acc1[2]);
      acc1[3] = fmaf(p1, v4.w, acc1[3]);
    }
    __syncthreads();
  }
  float* Op = Opart + (size_t)ks * S * E;
  float4 o0 = {acc0[0], acc0[1], acc0[2], acc0[3]};
  float4 o1 = {acc1[0], acc1[1], acc1[2], acc1[3]};
  *(float4*)(Op + (s0 + si) * E + h * DK + td) = o0;
  *(float4*)(Op + (s0 + si + 1) * E + h * DK + td) = o1;
}

// ---------------------------------------------------------------------------
// Combine K-split partials and normalize: ATT[s][e] = inv * sum_ks Opart.
// ---------------------------------------------------------------------------
__global__ __launch_bounds__(128) void combine_kernel(
    const float* __restrict__ Opart, const float* __restrict__ Inv,
    float* __restrict__ ATT) {
  const int s = blockIdx.x;
  const int e = threadIdx.x * 4;
  const int h = e >> 6;
  const float inv = Inv[h * S + s];
  float4 o = {0.0f, 0.0f, 0.0f, 0.0f};
  #pragma unroll
  for (int x = 0; x < 4; ++x) {
    float4 p = *(const float4*)(Opart + (size_t)x * S * E + s * E + e);
    o.x += p.x; o.y += p.y; o.z += p.z; o.w += p.w;
  }
  o.x *= inv; o.y *= inv; o.z *= inv; o.w *= inv;
  *(float4*)(ATT + s * E + e) = o;
}

// ---------------------------------------------------------------------------
// Launch
// ---------------------------------------------------------------------------
extern "C" void kernel_launch(void* const* d_in, const int* in_sizes, int n_in,
                              void* d_out, int out_size, void* d_ws, size_t ws_size,
                              hipStream_t stream) {
  const float* x    = (const float*)d_in[0];
  const float* Wq   = (const float*)d_in[1];
  const float* bq   = (const float*)d_in[2];
  const float* Wk   = (const float*)d_in[3];
  const float* bk   = (const float*)d_in[4];
  const float* Wv   = (const float*)d_in[5];
  const float* bv   = (const float*)d_in[6];
  const float* Wo   = (const float*)d_in[7];
  const float* bo   = (const float*)d_in[8];
  const float* iqW  = (const float*)d_in[9];
  const float* iqb  = (const float*)d_in[10];
  const float* ikW  = (const float*)d_in[11];
  const float* ikb  = (const float*)d_in[12];
  const float* wpW  = (const float*)d_in[13];
  const float* wpb  = (const float*)d_in[14];

  float* ws = (float*)d_ws;
  float* Qb   = ws;                    // S*E (row-major)
  float* Khm  = Qb + S * E;            // S*E (head-major)
  float* Vhm  = Khm + S * E;           // S*E (head-major)
  float* QI   = Vhm + S * E;           // S*E
  float* KI   = QI + S * E;            // S*DK
  float* WI   = KI + S * DK;           // S*H
  float* ISC  = WI + S * H;            // S*S
  unsigned* Mask = (unsigned*)(ISC + S * S);  // S*24 words
  float* Mrow = (float*)(Mask + S * 24);      // H*S
  float* Inv  = Mrow + H * S;          // H*S
  float* P    = Inv + H * S;           // H*S*S
  float* Opart= P + (size_t)H * S * S; // 4*S*E
  float* ATT  = Opart + 4 * S * E;     // S*E

  SegTable tab;
  tab.W[0] = Wq;  tab.b[0] = bq;  tab.out[0] = Qb;
  tab.W[1] = Wk;  tab.b[1] = bk;  tab.out[1] = Khm;
  tab.W[2] = Wv;  tab.b[2] = bv;  tab.out[2] = Vhm;
  tab.W[3] = iqW; tab.b[3] = iqb; tab.out[3] = QI;
  tab.W[4] = ikW; tab.b[4] = ikb; tab.out[4] = KI;
  tab.W[5] = wpW; tab.b[5] = wpb; tab.out[5] = WI;

  fused_proj_kernel<<<dim3(34, S / TM), dim3(256), 0, stream>>>(x, tab);
  indexer_kernel<<<dim3(S / 64, S / 32), dim3(256), 0, stream>>>(QI, KI, WI, ISC);
  topk_kernel<<<dim3(S), dim3(512), 0, stream>>>(ISC, Mask);
  score_kernel<<<dim3(S / 64, S / 64, H), dim3(256), 0, stream>>>(Qb, Khm, Mask, P);
  stats_kernel<<<dim3(H * S / 4), dim3(256), 0, stream>>>(P, Mrow, Inv);
  pv_kernel<<<dim3(4, S / 32, H), dim3(256), 0, stream>>>(P, Vhm, Mrow, Opart);
  combine_kernel<<<dim3(S), dim3(128), 0, stream>>>(Opart, Inv, ATT);
  gemm_bias64<<<dim3(E / TN, S / TM), dim3(256), 0, stream>>>(ATT, Wo, bo, (float*)d_out, E, E);
}

// Round 7
// 232.279 us; speedup vs baseline: 1.8174x; 1.0946x over previous
//
#include <hip/hip_runtime.h>
#include <hip/hip_bf16.h>
#include <math.h>

// Problem constants
#define S 768
#define E 512
#define H 8
#define DK 64
#define TOPK 384

#define TM 64
#define TN 64
#define BK 16

#define PCOLS 2120          // 4*512 + 64 + 8 concatenated projection cols
#define PF4   (PCOLS / 4)   // 530

// ---------------------------------------------------------------------------
// Fused projections, split-K=2: pure GEMM partials into PPr[2][S][PCOLS].
// Bias + per-seg routing happens in proj_combine.
// grid (34 n-tiles, 12 m-tiles, 2 k-halves), 256 threads, 4x4 per thread.
// ---------------------------------------------------------------------------
struct SegTable {
  const float* W[6];
};

__global__ __launch_bounds__(256) void fused_proj_kernel(
    const float* __restrict__ A, SegTable tab, float* __restrict__ PPr) {
  __shared__ __align__(16) float As[BK][TM + 4];   // pitch 68: 4*68%32=16 -> 2-way (free)
  __shared__ __align__(16) float Ws[BK][TN + 4];
  const int bx = blockIdx.x;
  int seg, nt;
  if (bx < 32) { seg = bx >> 3; nt = bx & 7; }
  else         { seg = 4 + (bx - 32); nt = 0; }
  const int N = (seg < 4) ? 512 : (seg == 4 ? 64 : 8);
  static const int segbase_tab[6] = {0, 512, 1024, 1536, 2048, 2112};
  const int colbase = segbase_tab[seg] + nt * TN;
  const float* __restrict__ W = tab.W[seg];
  const int m0 = blockIdx.y * TM;
  const int kbase = blockIdx.z * 256;

  const int tid = threadIdx.x;
  const int tm = (tid >> 4) << 2;
  const int tn = (tid & 15) << 2;
  const int am = tid >> 2;
  const int ac = tid & 3;
  const int wr = tid >> 4;
  const int wc = tid & 15;
  const bool fullN = (N >= TN);
  float acc[4][4] = {};
  for (int k0 = kbase; k0 < kbase + 256; k0 += BK) {
    float4 av = *(const float4*)(A + (m0 + am) * E + k0 + ac * 4);
    As[ac * 4 + 0][am] = av.x;
    As[ac * 4 + 1][am] = av.y;
    As[ac * 4 + 2][am] = av.z;
    As[ac * 4 + 3][am] = av.w;
    if (fullN) {
      *(float4*)&Ws[wr][wc * 4] = *(const float4*)(W + (k0 + wr) * N + wc * 4 + (colbase - segbase_tab[seg]));
    } else {
      #pragma unroll
      for (int j = 0; j < 4; ++j) {
        int n = wc * 4 + j;
        Ws[wr][wc * 4 + j] = (n < N) ? W[(k0 + wr) * N + n] : 0.0f;
      }
    }
    __syncthreads();
    #pragma unroll
    for (int k = 0; k < BK; ++k) {
      float4 a4 = *(const float4*)&As[k][tm];
      float4 w4 = *(const float4*)&Ws[k][tn];
      float ar[4] = {a4.x, a4.y, a4.z, a4.w};
      float wv[4] = {w4.x, w4.y, w4.z, w4.w};
      #pragma unroll
      for (int x = 0; x < 4; ++x)
        #pragma unroll
        for (int y = 0; y < 4; ++y)
          acc[x][y] = fmaf(ar[x], wv[y], acc[x][y]);
    }
    __syncthreads();
  }
  float* base = PPr + ((size_t)blockIdx.z * S) * PCOLS;
  #pragma unroll
  for (int x = 0; x < 4; ++x) {
    int m = m0 + tm + x;
    if (seg == 5 && tn >= 8) continue;
    float4 o = {acc[x][0], acc[x][1], acc[x][2], acc[x][3]};
    *(float4*)(base + (size_t)m * PCOLS + colbase + tn) = o;
  }
}

// ---------------------------------------------------------------------------
// Combine proj halves + bias, route to per-seg layouts.
// ---------------------------------------------------------------------------
struct BiasTable {
  const float* b[6];
};

__global__ __launch_bounds__(256) void proj_combine_kernel(
    const float* __restrict__ PPr, BiasTable bt,
    float* __restrict__ Qb, float* __restrict__ Khm, float* __restrict__ Vhm,
    float* __restrict__ QI, float* __restrict__ KI, float* __restrict__ WI) {
  const int s = blockIdx.x;
  const int tid = threadIdx.x;
  #pragma unroll
  for (int it = 0; it < 3; ++it) {
    int c4 = tid + it * 256;
    if (c4 >= PF4) break;
    int col = c4 * 4;
    const float* p0 = PPr + (size_t)s * PCOLS + col;
    const float* p1 = PPr + ((size_t)S + s) * PCOLS + col;
    float4 a = *(const float4*)p0;
    float4 b = *(const float4*)p1;
    float4 v = {a.x + b.x, a.y + b.y, a.z + b.z, a.w + b.w};
    const float* bp;
    float* dst;
    if (col < 512) {
      bp = bt.b[0] + col;            dst = Qb + s * 512 + col;
    } else if (col < 1024) {
      int n = col - 512;             bp = bt.b[1] + n;
      dst = Khm + (((n >> 6) * S + s) << 6) + (n & 63);
    } else if (col < 1536) {
      int n = col - 1024;            bp = bt.b[2] + n;
      dst = Vhm + (((n >> 6) * S + s) << 6) + (n & 63);
    } else if (col < 2048) {
      int n = col - 1536;            bp = bt.b[3] + n;  dst = QI + s * 512 + n;
    } else if (col < 2112) {
      int n = col - 2048;            bp = bt.b[4] + n;  dst = KI + s * 64 + n;
    } else {
      int n = col - 2112;            bp = bt.b[5] + n;  dst = WI + s * 8 + n;
    }
    float4 bb = *(const float4*)bp;
    float4 o = {v.x + bb.x, v.y + bb.y, v.z + bb.z, v.w + bb.w};
    *(float4*)dst = o;
  }
}

// ---------------------------------------------------------------------------
// Indexer (unchanged — keeps top-k selection bit-identical).
// ---------------------------------------------------------------------------
__global__ __launch_bounds__(256) void indexer_kernel(
    const float* __restrict__ QI, const float* __restrict__ KI,
    const float* __restrict__ WI, float* __restrict__ ISC) {
  __shared__ __align__(16) float ks[DK][68];
  __shared__ __align__(16) float qs[DK][36];
  const int tid = threadIdx.x;
  const int s0 = blockIdx.y * 32;
  const int t0 = blockIdx.x * 64;
  {
    int t = tid >> 2;
    int cb = tid & 3;
    #pragma unroll
    for (int cc = 0; cc < 4; ++cc) {
      int c = cb + cc * 4;
      float4 kv = *(const float4*)(KI + (t0 + t) * DK + c * 4);
      ks[c * 4 + 0][t] = kv.x;
      ks[c * 4 + 1][t] = kv.y;
      ks[c * 4 + 2][t] = kv.z;
      ks[c * 4 + 3][t] = kv.w;
    }
  }
  const int si = (tid >> 4) * 2;
  const int ti = (tid & 15) * 4;
  float acc[2][4] = {};
  for (int h = 0; h < H; ++h) {
    __syncthreads();
    #pragma unroll
    for (int r = 0; r < 2; ++r) {
      int idx = tid + r * 256;
      int s = idx >> 4;
      int c = idx & 15;
      float4 qv = *(const float4*)(QI + (s0 + s) * E + h * DK + c * 4);
      qs[c * 4 + 0][s] = qv.x;
      qs[c * 4 + 1][s] = qv.y;
      qs[c * 4 + 2][s] = qv.z;
      qs[c * 4 + 3][s] = qv.w;
    }
    __syncthreads();
    float dot[2][4] = {};
    #pragma unroll
    for (int d = 0; d < DK; ++d) {
      float4 kv = *(const float4*)&ks[d][ti];
      float kr[4] = {kv.x, kv.y, kv.z, kv.w};
      float q0 = qs[d][si];
      float q1 = qs[d][si + 1];
      #pragma unroll
      for (int j = 0; j < 4; ++j) {
        dot[0][j] = fmaf(q0, kr[j], dot[0][j]);
        dot[1][j] = fmaf(q1, kr[j], dot[1][j]);
      }
    }
    float w0 = WI[(s0 + si) * H + h];
    float w1 = WI[(s0 + si + 1) * H + h];
    #pragma unroll
    for (int j = 0; j < 4; ++j) {
      acc[0][j] += fmaxf(dot[0][j], 0.0f) * w0;
      acc[1][j] += fmaxf(dot[1][j], 0.0f) * w1;
    }
  }
  #pragma unroll
  for (int i = 0; i < 2; ++i) {
    float4 o = {acc[i][0], acc[i][1], acc[i][2], acc[i][3]};
    *(float4*)(ISC + (s0 + si + i) * S + t0 + ti) = o;
  }
}

// ---------------------------------------------------------------------------
// Top-k via bitonic sort (desc value, asc index == jax.lax.top_k ties).
// Emits 768-bit mask per row. Also zeroes Sum[h][s] for this row (free).
// ---------------------------------------------------------------------------
__global__ __launch_bounds__(512) void topk_kernel(
    const float* __restrict__ ISC, unsigned* __restrict__ Mask,
    float* __restrict__ Sum) {
  __shared__ float v[1024];
  __shared__ int   ix[1024];
  __shared__ unsigned mw[24];
  const int s = blockIdx.x;
  const int tid = threadIdx.x;
  for (int i = tid; i < 1024; i += 512) {
    v[i] = (i < S) ? ISC[s * S + i] : -3.402823466e38f;
    ix[i] = i;
  }
  if (tid < 24) mw[tid] = 0u;
  if (tid < H) Sum[tid * S + s] = 0.0f;
  __syncthreads();
  for (int k = 2; k <= 1024; k <<= 1) {
    for (int j = k >> 1; j > 0; j >>= 1) {
      #pragma unroll
      for (int t = tid; t < 1024; t += 512) {
        int l = t ^ j;
        if (l > t) {
          float vt = v[t], vl = v[l];
          int it = ix[t], il = ix[l];
          bool l_before_t = (vl > vt) || (vl == vt && il < it);
          bool up = ((t & k) == 0);
          if (up ? l_before_t : !l_before_t) {
            v[t] = vl; v[l] = vt;
            ix[t] = il; ix[l] = it;
          }
        }
      }
      __syncthreads();
    }
  }
  if (tid < TOPK) {
    int t = ix[tid];
    atomicOr(&mw[t >> 5], 1u << (t & 31));
  }
  __syncthreads();
  if (tid < 24) Mask[s * 24 + tid] = mw[tid];
}

// ---------------------------------------------------------------------------
// Dense masked scores, exp applied, row sums accumulated:
//   Pexp[h][s][t] = mask ? exp(dot*0.125) : 0 ;  Sum[h][s] += row partials.
// (No max-subtraction: |dot*0.125| <~ 1.5 by construction — exp is safe and
//  softmax is algebraically identical.)
// ---------------------------------------------------------------------------
__global__ __launch_bounds__(256) void score_kernel(
    const float* __restrict__ Q, const float* __restrict__ Khm,
    const unsigned* __restrict__ Mask, float* __restrict__ Pexp,
    float* __restrict__ Sum) {
  __shared__ __align__(16) float Qs[DK][68];
  __shared__ __align__(16) float Ks[DK][68];
  __shared__ float rs[64];
  const int h = blockIdx.z;
  const int s0 = blockIdx.y * 64;
  const int t0 = blockIdx.x * 64;
  const int tid = threadIdx.x;
  if (tid < 64) rs[tid] = 0.0f;
  #pragma unroll
  for (int j = 0; j < 4; ++j) {
    int i = tid + j * 256;
    int r = i >> 4, c = i & 15;
    float4 q4 = *(const float4*)(Q + (s0 + r) * E + h * DK + c * 4);
    Qs[c * 4 + 0][r] = q4.x;
    Qs[c * 4 + 1][r] = q4.y;
    Qs[c * 4 + 2][r] = q4.z;
    Qs[c * 4 + 3][r] = q4.w;
    float4 k4 = *(const float4*)(Khm + (h * S + t0 + r) * DK + c * 4);
    Ks[c * 4 + 0][r] = k4.x;
    Ks[c * 4 + 1][r] = k4.y;
    Ks[c * 4 + 2][r] = k4.z;
    Ks[c * 4 + 3][r] = k4.w;
  }
  __syncthreads();
  const int tm = (tid >> 4) << 2;
  const int tn = (tid & 15) << 2;
  float acc[4][4] = {};
  #pragma unroll 8
  for (int d = 0; d < DK; ++d) {
    float4 a4 = *(const float4*)&Qs[d][tm];
    float4 b4 = *(const float4*)&Ks[d][tn];
    float ar[4] = {a4.x, a4.y, a4.z, a4.w};
    float br[4] = {b4.x, b4.y, b4.z, b4.w};
    #pragma unroll
    for (int x = 0; x < 4; ++x)
      #pragma unroll
      for (int y = 0; y < 4; ++y)
        acc[x][y] = fmaf(ar[x], br[y], acc[x][y]);
  }
  const int wsh = tn & 31;
  #pragma unroll
  for (int x = 0; x < 4; ++x) {
    int s = s0 + tm + x;
    unsigned w = Mask[s * 24 + ((t0 + tn) >> 5)];
    float4 o;
    o.x = ((w >> (wsh + 0)) & 1u) ? __expf(acc[x][0] * 0.125f) : 0.0f;
    o.y = ((w >> (wsh + 1)) & 1u) ? __expf(acc[x][1] * 0.125f) : 0.0f;
    o.z = ((w >> (wsh + 2)) & 1u) ? __expf(acc[x][2] * 0.125f) : 0.0f;
    o.w = ((w >> (wsh + 3)) & 1u) ? __expf(acc[x][3] * 0.125f) : 0.0f;
    *(float4*)(Pexp + ((size_t)h * S + s) * S + t0 + tn) = o;
    atomicAdd(&rs[tm + x], o.x + o.y + o.z + o.w);
  }
  __syncthreads();
  if (tid < 64) atomicAdd(&Sum[h * S + s0 + tid], rs[tid]);
}

// ---------------------------------------------------------------------------
// PV GEMM (pure), K-split=4: Opart[ks][s][h*64+d] = sum_t Pexp * V.
// ---------------------------------------------------------------------------
__global__ __launch_bounds__(256) void pv_kernel(
    const float* __restrict__ Pexp, const float* __restrict__ Vhm,
    float* __restrict__ Opart) {
  __shared__ __align__(16) float Ps[16][36];   // [t][s]
  __shared__ __align__(16) float Vs[16][68];   // [t][d]
  const int ks = blockIdx.x;
  const int s0 = blockIdx.y * 32;
  const int h  = blockIdx.z;
  const int tid = threadIdx.x;
  const int si = (tid >> 4) << 1;
  const int td = (tid & 15) << 2;
  const size_t Pbase = ((size_t)h * S + s0) * S;
  float acc0[4] = {}, acc1[4] = {};
  for (int kt = 0; kt < 12; ++kt) {
    const int t0 = ks * 192 + kt * 16;
    if (tid < 128) {
      int r = tid >> 2, c = tid & 3;
      float4 p4 = *(const float4*)(Pexp + Pbase + (size_t)r * S + t0 + c * 4);
      Ps[c * 4 + 0][r] = p4.x;
      Ps[c * 4 + 1][r] = p4.y;
      Ps[c * 4 + 2][r] = p4.z;
      Ps[c * 4 + 3][r] = p4.w;
    }
    {
      int r = tid >> 4, c = tid & 15;
      float4 v4 = *(const float4*)(Vhm + ((size_t)h * S + t0 + r) * DK + c * 4);
      *(float4*)&Vs[r][c * 4] = v4;
    }
    __syncthreads();
    #pragma unroll
    for (int t = 0; t < 16; ++t) {
      float p0 = Ps[t][si];
      float p1 = Ps[t][si + 1];
      float4 v4 = *(const float4*)&Vs[t][td];
      acc0[0] = fmaf(p0, v4.x, acc0[0]);
      acc0[1] = fmaf(p0, v4.y, acc0[1]);
      acc0[2] = fmaf(p0, v4.z, acc0[2]);
      acc0[3] = fmaf(p0, v4.w, acc0[3]);
      acc1[0] = fmaf(p1, v4.x, acc1[0]);
      acc1[1] = fmaf(p1, v4.y, acc1[1]);
      acc1[2] = fmaf(p1, v4.z, acc1[2]);
      acc1[3] = fmaf(p1, v4.w, acc1[3]);
    }
    __syncthreads();
  }
  float* Op = Opart + (size_t)ks * S * E;
  float4 o0 = {acc0[0], acc0[1], acc0[2], acc0[3]};
  float4 o1 = {acc1[0], acc1[1], acc1[2], acc1[3]};
  *(float4*)(Op + (s0 + si) * E + h * DK + td) = o0;
  *(float4*)(Op + (s0 + si + 1) * E + h * DK + td) = o1;
}

// ---------------------------------------------------------------------------
// Combine PV partials and normalize by row sums.
// ---------------------------------------------------------------------------
__global__ __launch_bounds__(128) void combine_kernel(
    const float* __restrict__ Opart, const float* __restrict__ Sum,
    float* __restrict__ ATT) {
  const int s = blockIdx.x;
  const int e = threadIdx.x * 4;
  const int h = e >> 6;
  const float inv = 1.0f / Sum[h * S + s];
  float4 o = {0.0f, 0.0f, 0.0f, 0.0f};
  #pragma unroll
  for (int x = 0; x < 4; ++x) {
    float4 p = *(const float4*)(Opart + (size_t)x * S * E + s * E + e);
    o.x += p.x; o.y += p.y; o.z += p.z; o.w += p.w;
  }
  o.x *= inv; o.y *= inv; o.z *= inv; o.w *= inv;
  *(float4*)(ATT + s * E + e) = o;
}

// ---------------------------------------------------------------------------
// Output projection split-K=4 (pure partials), then bias-combine.
// ---------------------------------------------------------------------------
__global__ __launch_bounds__(256) void out_part_kernel(
    const float* __restrict__ A, const float* __restrict__ W,
    float* __restrict__ OoPart) {
  __shared__ __align__(16) float As[BK][TM + 4];
  __shared__ __align__(16) float Ws[BK][TN + 4];
  const int n0 = blockIdx.x * TN;
  const int m0 = blockIdx.y * TM;
  const int kbase = blockIdx.z * 128;
  const int tid = threadIdx.x;
  const int tm = (tid >> 4) << 2;
  const int tn = (tid & 15) << 2;
  const int am = tid >> 2;
  const int ac = tid & 3;
  const int wr = tid >> 4;
  const int wc = tid & 15;
  float acc[4][4] = {};
  for (int k0 = kbase; k0 < kbase + 128; k0 += BK) {
    float4 av = *(const float4*)(A + (m0 + am) * E + k0 + ac * 4);
    As[ac * 4 + 0][am] = av.x;
    As[ac * 4 + 1][am] = av.y;
    As[ac * 4 + 2][am] = av.z;
    As[ac * 4 + 3][am] = av.w;
    *(float4*)&Ws[wr][wc * 4] = *(const float4*)(W + (k0 + wr) * E + n0 + wc * 4);
    __syncthreads();
    #pragma unroll
    for (int k = 0; k < BK; ++k) {
      float4 a4 = *(const float4*)&As[k][tm];
      float4 w4 = *(const float4*)&Ws[k][tn];
      float ar[4] = {a4.x, a4.y, a4.z, a4.w};
      float wv[4] = {w4.x, w4.y, w4.z, w4.w};
      #pragma unroll
      for (int x = 0; x < 4; ++x)
        #pragma unroll
        for (int y = 0; y < 4; ++y)
          acc[x][y] = fmaf(ar[x], wv[y], acc[x][y]);
    }
    __syncthreads();
  }
  float* Op = OoPart + (size_t)blockIdx.z * S * E;
  #pragma unroll
  for (int x = 0; x < 4; ++x) {
    float4 o = {acc[x][0], acc[x][1], acc[x][2], acc[x][3]};
    *(float4*)(Op + (size_t)(m0 + tm + x) * E + n0 + tn) = o;
  }
}

__global__ __launch_bounds__(128) void out_combine_kernel(
    const float* __restrict__ OoPart, const float* __restrict__ bo,
    float* __restrict__ out) {
  const int s = blockIdx.x;
  const int e = threadIdx.x * 4;
  float4 o = *(const float4*)(bo + e);
  #pragma unroll
  for (int x = 0; x < 4; ++x) {
    float4 p = *(const float4*)(OoPart + (size_t)x * S * E + s * E + e);
    o.x += p.x; o.y += p.y; o.z += p.z; o.w += p.w;
  }
  *(float4*)(out + s * E + e) = o;
}

// ---------------------------------------------------------------------------
// Launch
// ---------------------------------------------------------------------------
extern "C" void kernel_launch(void* const* d_in, const int* in_sizes, int n_in,
                              void* d_out, int out_size, void* d_ws, size_t ws_size,
                              hipStream_t stream) {
  const float* x    = (const float*)d_in[0];
  const float* Wq   = (const float*)d_in[1];
  const float* bq   = (const float*)d_in[2];
  const float* Wk   = (const float*)d_in[3];
  const float* bk   = (const float*)d_in[4];
  const float* Wv   = (const float*)d_in[5];
  const float* bv   = (const float*)d_in[6];
  const float* Wo   = (const float*)d_in[7];
  const float* bo   = (const float*)d_in[8];
  const float* iqW  = (const float*)d_in[9];
  const float* iqb  = (const float*)d_in[10];
  const float* ikW  = (const float*)d_in[11];
  const float* ikb  = (const float*)d_in[12];
  const float* wpW  = (const float*)d_in[13];
  const float* wpb  = (const float*)d_in[14];

  float* ws = (float*)d_ws;
  float* Qb   = ws;                    // S*E
  float* Khm  = Qb + S * E;            // S*E (head-major)
  float* Vhm  = Khm + S * E;           // S*E (head-major)
  float* QI   = Vhm + S * E;           // S*E
  float* KI   = QI + S * E;            // S*DK
  float* WI   = KI + S * DK;           // S*H
  float* ISC  = WI + S * H;            // S*S
  unsigned* Mask = (unsigned*)(ISC + S * S);  // S*24 words
  float* Sum  = (float*)(Mask + S * 24);      // H*S
  float* BIG  = Sum + H * S;           // max(PPr 2*S*PCOLS, Pexp H*S*S, OoPart 4*S*E)
  float* PPr  = BIG;                   // 2*S*2120 = 3.26M  (dead after proj_combine)
  float* Pexp = BIG;                   // H*S*S    = 4.72M  (score..pv)
  float* OoPart = BIG;                 // 4*S*E    = 1.57M  (after pv)
  float* Opart = BIG + (size_t)H * S * S;  // 4*S*E
  float* ATT  = Opart + 4 * S * E;     // S*E

  SegTable tab;
  tab.W[0] = Wq; tab.W[1] = Wk; tab.W[2] = Wv;
  tab.W[3] = iqW; tab.W[4] = ikW; tab.W[5] = wpW;
  BiasTable bt;
  bt.b[0] = bq; bt.b[1] = bk; bt.b[2] = bv;
  bt.b[3] = iqb; bt.b[4] = ikb; bt.b[5] = wpb;

  // projections: 34 x 12 x 2 = 816 blocks (split-K)
  fused_proj_kernel<<<dim3(34, S / TM, 2), dim3(256), 0, stream>>>(x, tab, PPr);
  proj_combine_kernel<<<dim3(S), dim3(256), 0, stream>>>(PPr, bt, Qb, Khm, Vhm, QI, KI, WI);
  // indexer scores: 288 blocks
  indexer_kernel<<<dim3(S / 64, S / 32), dim3(256), 0, stream>>>(QI, KI, WI, ISC);
  // top-k per row (also zeroes Sum)
  topk_kernel<<<dim3(S), dim3(512), 0, stream>>>(ISC, Mask, Sum);
  // masked exp scores + row sums: 1152 blocks
  score_kernel<<<dim3(S / 64, S / 64, H), dim3(256), 0, stream>>>(Qb, Khm, Mask, Pexp, Sum);
  // PV partials: 768 blocks
  pv_kernel<<<dim3(4, S / 32, H), dim3(256), 0, stream>>>(Pexp, Vhm, Opart);
  // normalize + combine
  combine_kernel<<<dim3(S), dim3(128), 0, stream>>>(Opart, Sum, ATT);
  // output projection: 8 x 12 x 4 = 384 blocks (split-K) + bias combine
  out_part_kernel<<<dim3(E / TN, S / TM, 4), dim3(256), 0, stream>>>(ATT, Wo, OoPart);
  out_combine_kernel<<<dim3(S), dim3(128), 0, stream>>>(OoPart, bo, (float*)d_out);
}

// Round 8
// 198.069 us; speedup vs baseline: 2.1312x; 1.1727x over previous
//
#include <hip/hip_runtime.h>
#include <hip/hip_bf16.h>
#include <math.h>

// Problem constants
#define S 768
#define E 512
#define H 8
#define DK 64
#define TOPK 384

#define TM 64
#define TN 64
#define BK 16

// ---------------------------------------------------------------------------
// Fused projections, INTERNAL split-K (512 threads: half z does K range
// [z*256, z*256+256)), halves summed via LDS; bias + per-seg routing in the
// epilogue. Grid (34 n-tiles, 12 m-tiles).
// ---------------------------------------------------------------------------
struct SegTable {
  const float* W[6];
  const float* b[6];
};

__global__ __launch_bounds__(512) void fused_proj_kernel(
    const float* __restrict__ A, SegTable tab,
    float* __restrict__ Qb, float* __restrict__ Khm, float* __restrict__ Vhm,
    float* __restrict__ QI, float* __restrict__ KI, float* __restrict__ WI) {
  __shared__ __align__(16) float As[2][BK][TM + 4];
  __shared__ __align__(16) float Ws[2][BK][TN + 4];
  __shared__ __align__(16) float AccL[TM][TN + 4];
  const int bx = blockIdx.x;
  int seg, nt;
  if (bx < 32) { seg = bx >> 3; nt = bx & 7; }
  else         { seg = 4 + (bx - 32); nt = 0; }
  const int N = (seg < 4) ? 512 : (seg == 4 ? 64 : 8);
  const float* __restrict__ W = tab.W[seg];
  const int m0 = blockIdx.y * TM;
  const int tid512 = threadIdx.x;
  const int z   = tid512 >> 8;       // K-half
  const int tid = tid512 & 255;
  const int kbase = z * 256;
  const int tm = (tid >> 4) << 2;
  const int tn = (tid & 15) << 2;
  const int am = tid >> 2;
  const int ac = tid & 3;
  const int wr = tid >> 4;
  const int wc = tid & 15;
  const int n0 = nt * TN;
  const bool fullN = (N >= TN);
  float acc[4][4] = {};
  for (int k0 = kbase; k0 < kbase + 256; k0 += BK) {
    float4 av = *(const float4*)(A + (m0 + am) * E + k0 + ac * 4);
    As[z][ac * 4 + 0][am] = av.x;
    As[z][ac * 4 + 1][am] = av.y;
    As[z][ac * 4 + 2][am] = av.z;
    As[z][ac * 4 + 3][am] = av.w;
    if (fullN) {
      *(float4*)&Ws[z][wr][wc * 4] = *(const float4*)(W + (k0 + wr) * N + n0 + wc * 4);
    } else {
      #pragma unroll
      for (int j = 0; j < 4; ++j) {
        int n = wc * 4 + j;
        Ws[z][wr][wc * 4 + j] = (n < N) ? W[(k0 + wr) * N + n] : 0.0f;
      }
    }
    __syncthreads();
    #pragma unroll
    for (int k = 0; k < BK; ++k) {
      float4 a4 = *(const float4*)&As[z][k][tm];
      float4 w4 = *(const float4*)&Ws[z][k][tn];
      float ar[4] = {a4.x, a4.y, a4.z, a4.w};
      float wv[4] = {w4.x, w4.y, w4.z, w4.w};
      #pragma unroll
      for (int x = 0; x < 4; ++x)
        #pragma unroll
        for (int y = 0; y < 4; ++y)
          acc[x][y] = fmaf(ar[x], wv[y], acc[x][y]);
    }
    __syncthreads();
  }
  if (z == 1) {
    #pragma unroll
    for (int x = 0; x < 4; ++x) {
      float4 o = {acc[x][0], acc[x][1], acc[x][2], acc[x][3]};
      *(float4*)&AccL[tm + x][tn] = o;
    }
  }
  __syncthreads();
  if (z == 0) {
    const float* __restrict__ bias = tab.b[seg];
    #pragma unroll
    for (int x = 0; x < 4; ++x) {
      float4 p = *(const float4*)&AccL[tm + x][tn];
      acc[x][0] += p.x; acc[x][1] += p.y; acc[x][2] += p.z; acc[x][3] += p.w;
    }
    if (seg == 0 || seg == 3) {
      float* dst = (seg == 0) ? Qb : QI;
      float4 b4 = *(const float4*)(bias + n0 + tn);
      #pragma unroll
      for (int x = 0; x < 4; ++x) {
        int m = m0 + tm + x;
        float4 o = {acc[x][0] + b4.x, acc[x][1] + b4.y,
                    acc[x][2] + b4.z, acc[x][3] + b4.w};
        *(float4*)(dst + m * 512 + n0 + tn) = o;
      }
    } else if (seg == 1 || seg == 2) {
      float* dst = ((seg == 1) ? Khm : Vhm) + nt * (S * DK);   // head = nt
      float4 b4 = *(const float4*)(bias + n0 + tn);
      #pragma unroll
      for (int x = 0; x < 4; ++x) {
        int m = m0 + tm + x;
        float4 o = {acc[x][0] + b4.x, acc[x][1] + b4.y,
                    acc[x][2] + b4.z, acc[x][3] + b4.w};
        *(float4*)(dst + m * DK + tn) = o;
      }
    } else if (seg == 4) {
      float4 b4 = *(const float4*)(bias + tn);
      #pragma unroll
      for (int x = 0; x < 4; ++x) {
        int m = m0 + tm + x;
        float4 o = {acc[x][0] + b4.x, acc[x][1] + b4.y,
                    acc[x][2] + b4.z, acc[x][3] + b4.w};
        *(float4*)(KI + m * 64 + tn) = o;
      }
    } else {
      if (tn < 8) {
        #pragma unroll
        for (int x = 0; x < 4; ++x) {
          int m = m0 + tm + x;
          #pragma unroll
          for (int y = 0; y < 4; ++y) {
            int n = tn + y;
            if (n < 8) WI[m * 8 + n] = acc[x][y] + bias[n];
          }
        }
      }
    }
  }
}

// ---------------------------------------------------------------------------
// Indexer (unchanged — keeps top-k selection input bit-identical).
// ---------------------------------------------------------------------------
__global__ __launch_bounds__(256) void indexer_kernel(
    const float* __restrict__ QI, const float* __restrict__ KI,
    const float* __restrict__ WI, float* __restrict__ ISC) {
  __shared__ __align__(16) float ks[DK][68];
  __shared__ __align__(16) float qs[DK][36];
  const int tid = threadIdx.x;
  const int s0 = blockIdx.y * 32;
  const int t0 = blockIdx.x * 64;
  {
    int t = tid >> 2;
    int cb = tid & 3;
    #pragma unroll
    for (int cc = 0; cc < 4; ++cc) {
      int c = cb + cc * 4;
      float4 kv = *(const float4*)(KI + (t0 + t) * DK + c * 4);
      ks[c * 4 + 0][t] = kv.x;
      ks[c * 4 + 1][t] = kv.y;
      ks[c * 4 + 2][t] = kv.z;
      ks[c * 4 + 3][t] = kv.w;
    }
  }
  const int si = (tid >> 4) * 2;
  const int ti = (tid & 15) * 4;
  float acc[2][4] = {};
  for (int h = 0; h < H; ++h) {
    __syncthreads();
    #pragma unroll
    for (int r = 0; r < 2; ++r) {
      int idx = tid + r * 256;
      int s = idx >> 4;
      int c = idx & 15;
      float4 qv = *(const float4*)(QI + (s0 + s) * E + h * DK + c * 4);
      qs[c * 4 + 0][s] = qv.x;
      qs[c * 4 + 1][s] = qv.y;
      qs[c * 4 + 2][s] = qv.z;
      qs[c * 4 + 3][s] = qv.w;
    }
    __syncthreads();
    float dot[2][4] = {};
    #pragma unroll
    for (int d = 0; d < DK; ++d) {
      float4 kv = *(const float4*)&ks[d][ti];
      float kr[4] = {kv.x, kv.y, kv.z, kv.w};
      float q0 = qs[d][si];
      float q1 = qs[d][si + 1];
      #pragma unroll
      for (int j = 0; j < 4; ++j) {
        dot[0][j] = fmaf(q0, kr[j], dot[0][j]);
        dot[1][j] = fmaf(q1, kr[j], dot[1][j]);
      }
    }
    float w0 = WI[(s0 + si) * H + h];
    float w1 = WI[(s0 + si + 1) * H + h];
    #pragma unroll
    for (int j = 0; j < 4; ++j) {
      acc[0][j] += fmaxf(dot[0][j], 0.0f) * w0;
      acc[1][j] += fmaxf(dot[1][j], 0.0f) * w1;
    }
  }
  #pragma unroll
  for (int i = 0; i < 2; ++i) {
    float4 o = {acc[i][0], acc[i][1], acc[i][2], acc[i][3]};
    *(float4*)(ISC + (s0 + si + i) * S + t0 + ti) = o;
  }
}

// ---------------------------------------------------------------------------
// Top-k via exact radix select (4 x 8-bit passes on orderable uints).
// Selected set == jax.lax.top_k stable-ties: all > thr, plus first
// (384 - cnt_gt) indices with value == thr. -0.0 canonicalized to +0.0 so
// zero-ties break by index. Emits 768-bit mask, zeroes Sum.
// ---------------------------------------------------------------------------
__global__ __launch_bounds__(256) void topk_kernel(
    const float* __restrict__ ISC, unsigned* __restrict__ Mask,
    float* __restrict__ Sum) {
  __shared__ unsigned ordv[768];
  __shared__ int hist[256];
  __shared__ int gsum[16];
  __shared__ int sc[256];
  __shared__ unsigned mw[24];
  __shared__ unsigned sh_prefix;
  __shared__ int sh_R;
  const int s = blockIdx.x;
  const int tid = threadIdx.x;
  for (int i = tid; i < 768; i += 256) {
    float f = ISC[s * 768 + i] + 0.0f;            // -0.0 -> +0.0
    unsigned u = __float_as_uint(f);
    ordv[i] = (u & 0x80000000u) ? ~u : (u | 0x80000000u);
  }
  if (tid < 24) mw[tid] = 0u;
  if (tid < H) Sum[tid * S + s] = 0.0f;
  if (tid == 0) { sh_prefix = 0u; sh_R = TOPK; }
  __syncthreads();
  for (int pass = 0; pass < 4; ++pass) {
    const int shift = 24 - pass * 8;
    hist[tid] = 0;
    __syncthreads();
    const unsigned pm = (pass == 0) ? 0u : (0xFFFFFFFFu << (shift + 8));
    const unsigned pref = sh_prefix;
    for (int i = tid; i < 768; i += 256) {
      unsigned o = ordv[i];
      if ((o & pm) == pref) atomicAdd(&hist[(o >> shift) & 255], 1);
    }
    __syncthreads();
    if (tid < 16) {
      int t = 0;
      #pragma unroll
      for (int k = 0; k < 16; ++k) t += hist[tid * 16 + k];
      gsum[tid] = t;
    }
    __syncthreads();
    if (tid == 0) {
      int R = sh_R;
      int G = 0;
      int g = 15;
      for (; g > 0; --g) {
        if (G + gsum[g] >= R) break;
        G += gsum[g];
      }
      int b = 15;
      for (; b > 0; --b) {
        int c = hist[g * 16 + b];
        if (G + c >= R) break;
        G += c;
      }
      sh_prefix = sh_prefix | ((unsigned)(g * 16 + b) << shift);
      sh_R = R - G;       // equals still needed at this refinement level
    }
    __syncthreads();
  }
  const unsigned thr = sh_prefix;
  const int need_eq = sh_R;
  // rank equals by index: each thread owns 3 contiguous elements
  const int base = tid * 3;
  unsigned o0 = ordv[base], o1 = ordv[base + 1], o2 = ordv[base + 2];
  int c = (o0 == thr) + (o1 == thr) + (o2 == thr);
  sc[tid] = c;
  __syncthreads();
  for (int off = 1; off < 256; off <<= 1) {
    int v = (tid >= off) ? sc[tid - off] : 0;
    __syncthreads();
    sc[tid] += v;
    __syncthreads();
  }
  int rank = sc[tid] - c;          // exclusive prefix count of equals
  if (o0 > thr || (o0 == thr && rank < need_eq))
    atomicOr(&mw[base >> 5], 1u << (base & 31));
  if (o0 == thr) ++rank;
  if (o1 > thr || (o1 == thr && rank < need_eq))
    atomicOr(&mw[(base + 1) >> 5], 1u << ((base + 1) & 31));
  if (o1 == thr) ++rank;
  if (o2 > thr || (o2 == thr && rank < need_eq))
    atomicOr(&mw[(base + 2) >> 5], 1u << ((base + 2) & 31));
  __syncthreads();
  if (tid < 24) Mask[s * 24 + tid] = mw[tid];
}

// ---------------------------------------------------------------------------
// Fused masked attention (score+exp+PV), flash-style with t-chunk split:
// block = (ks in 0..3, 32-row s-tile, h). P tile lives only in LDS.
// Partial O -> Opart[ks]; row exp-sums -> atomicAdd Sum (zeroed by topk).
// No max-subtraction: |score| <~ 1.5 by construction, exp is safe in fp32.
// ---------------------------------------------------------------------------
__global__ __launch_bounds__(256) void sattn_kernel(
    const float* __restrict__ Q, const float* __restrict__ Khm,
    const float* __restrict__ Vhm, const unsigned* __restrict__ Mask,
    float* __restrict__ Opart, float* __restrict__ Sum) {
  __shared__ __align__(16) float Qs[32][DK + 4];   // [s][d]
  __shared__ __align__(16) float Ks[16][DK + 4];   // [t][d]
  __shared__ __align__(16) float Vs[16][DK + 4];   // [t][d]
  __shared__ __align__(16) float Ps[16][36];       // [t][s]
  __shared__ unsigned msk[32][6];
  __shared__ float rsum[8][32];
  const int ks = blockIdx.x;
  const int s0 = blockIdx.y * 32;
  const int h  = blockIdx.z;
  const int tid = threadIdx.x;
  const int tbase = ks * 192;
  // stage Q tile (32 x 64) and mask words (32 rows x 6 words)
  #pragma unroll
  for (int j = 0; j < 2; ++j) {
    int idx = tid + j * 256;
    int r = idx >> 4, cc = idx & 15;
    *(float4*)&Qs[r][cc * 4] =
        *(const float4*)(Q + (s0 + r) * E + h * DK + cc * 4);
  }
  if (tid < 192) {
    int r = tid & 31, j = tid >> 5;
    msk[r][j] = Mask[(s0 + r) * 24 + (tbase >> 5) + j];
  }
  const int ssc = tid & 31;          // score row
  const int tg  = tid >> 5;          // 0..7 -> t pair
  const int si = (tid >> 4) << 1;    // PV: output rows
  const int td = (tid & 15) << 2;    // PV: output dims
  float psum = 0.0f;
  float a0[4] = {}, a1[4] = {};
  for (int kt = 0; kt < 12; ++kt) {
    const int trow = tbase + kt * 16;
    __syncthreads();    // prev PV done (and initial staging visible)
    {
      int r = tid >> 4, cc = tid & 15;
      *(float4*)&Ks[r][cc * 4] =
          *(const float4*)(Khm + (size_t)(h * S + trow + r) * DK + cc * 4);
      *(float4*)&Vs[r][cc * 4] =
          *(const float4*)(Vhm + (size_t)(h * S + trow + r) * DK + cc * 4);
    }
    __syncthreads();
    {
      const int t0 = tg * 2, t1 = t0 + 1;
      float d0 = 0.0f, d1 = 0.0f;
      #pragma unroll
      for (int c4 = 0; c4 < 16; ++c4) {
        float4 qv = *(const float4*)&Qs[ssc][c4 * 4];
        float4 k0 = *(const float4*)&Ks[t0][c4 * 4];
        float4 k1 = *(const float4*)&Ks[t1][c4 * 4];
        d0 = fmaf(qv.x, k0.x, d0); d0 = fmaf(qv.y, k0.y, d0);
        d0 = fmaf(qv.z, k0.z, d0); d0 = fmaf(qv.w, k0.w, d0);
        d1 = fmaf(qv.x, k1.x, d1); d1 = fmaf(qv.y, k1.y, d1);
        d1 = fmaf(qv.z, k1.z, d1); d1 = fmaf(qv.w, k1.w, d1);
      }
      int tt0 = kt * 16 + t0, tt1 = tt0 + 1;
      unsigned w0 = msk[ssc][tt0 >> 5];
      float e0 = ((w0 >> (tt0 & 31)) & 1u) ? __expf(d0 * 0.125f) : 0.0f;
      float e1 = ((w0 >> (tt1 & 31)) & 1u) ? __expf(d1 * 0.125f) : 0.0f;
      Ps[t0][ssc] = e0;
      Ps[t1][ssc] = e1;
      psum += e0 + e1;
    }
    __syncthreads();
    #pragma unroll
    for (int t = 0; t < 16; ++t) {
      float p0 = Ps[t][si];
      float p1 = Ps[t][si + 1];
      float4 v4 = *(const float4*)&Vs[t][td];
      a0[0] = fmaf(p0, v4.x, a0[0]); a0[1] = fmaf(p0, v4.y, a0[1]);
      a0[2] = fmaf(p0, v4.z, a0[2]); a0[3] = fmaf(p0, v4.w, a0[3]);
      a1[0] = fmaf(p1, v4.x, a1[0]); a1[1] = fmaf(p1, v4.y, a1[1]);
      a1[2] = fmaf(p1, v4.z, a1[2]); a1[3] = fmaf(p1, v4.w, a1[3]);
    }
  }
  rsum[tg][ssc] = psum;
  __syncthreads();
  if (tid < 32) {
    float t = 0.0f;
    #pragma unroll
    for (int g = 0; g < 8; ++g) t += rsum[g][tid];
    atomicAdd(&Sum[h * S + s0 + tid], t);
  }
  float* Op = Opart + (size_t)ks * S * E;
  float4 o0 = {a0[0], a0[1], a0[2], a0[3]};
  float4 o1 = {a1[0], a1[1], a1[2], a1[3]};
  *(float4*)(Op + (size_t)(s0 + si) * E + h * DK + td) = o0;
  *(float4*)(Op + (size_t)(s0 + si + 1) * E + h * DK + td) = o1;
}

// ---------------------------------------------------------------------------
// Combine PV partials and normalize by row sums.
// ---------------------------------------------------------------------------
__global__ __launch_bounds__(128) void combine_kernel(
    const float* __restrict__ Opart, const float* __restrict__ Sum,
    float* __restrict__ ATT) {
  const int s = blockIdx.x;
  const int e = threadIdx.x * 4;
  const int h = e >> 6;
  const float inv = 1.0f / Sum[h * S + s];
  float4 o = {0.0f, 0.0f, 0.0f, 0.0f};
  #pragma unroll
  for (int x = 0; x < 4; ++x) {
    float4 p = *(const float4*)(Opart + (size_t)x * S * E + s * E + e);
    o.x += p.x; o.y += p.y; o.z += p.z; o.w += p.w;
  }
  o.x *= inv; o.y *= inv; o.z *= inv; o.w *= inv;
  *(float4*)(ATT + s * E + e) = o;
}

// ---------------------------------------------------------------------------
// Output projection split-K=4 (pure partials), then bias-combine.
// ---------------------------------------------------------------------------
__global__ __launch_bounds__(256) void out_part_kernel(
    const float* __restrict__ A, const float* __restrict__ W,
    float* __restrict__ OoPart) {
  __shared__ __align__(16) float As[BK][TM + 4];
  __shared__ __align__(16) float Ws[BK][TN + 4];
  const int n0 = blockIdx.x * TN;
  const int m0 = blockIdx.y * TM;
  const int kbase = blockIdx.z * 128;
  const int tid = threadIdx.x;
  const int tm = (tid >> 4) << 2;
  const int tn = (tid & 15) << 2;
  const int am = tid >> 2;
  const int ac = tid & 3;
  const int wr = tid >> 4;
  const int wc = tid & 15;
  float acc[4][4] = {};
  for (int k0 = kbase; k0 < kbase + 128; k0 += BK) {
    float4 av = *(const float4*)(A + (m0 + am) * E + k0 + ac * 4);
    As[ac * 4 + 0][am] = av.x;
    As[ac * 4 + 1][am] = av.y;
    As[ac * 4 + 2][am] = av.z;
    As[ac * 4 + 3][am] = av.w;
    *(float4*)&Ws[wr][wc * 4] = *(const float4*)(W + (k0 + wr) * E + n0 + wc * 4);
    __syncthreads();
    #pragma unroll
    for (int k = 0; k < BK; ++k) {
      float4 a4 = *(const float4*)&As[k][tm];
      float4 w4 = *(const float4*)&Ws[k][tn];
      float ar[4] = {a4.x, a4.y, a4.z, a4.w};
      float wv[4] = {w4.x, w4.y, w4.z, w4.w};
      #pragma unroll
      for (int x = 0; x < 4; ++x)
        #pragma unroll
        for (int y = 0; y < 4; ++y)
          acc[x][y] = fmaf(ar[x], wv[y], acc[x][y]);
    }
    __syncthreads();
  }
  float* Op = OoPart + (size_t)blockIdx.z * S * E;
  #pragma unroll
  for (int x = 0; x < 4; ++x) {
    float4 o = {acc[x][0], acc[x][1], acc[x][2], acc[x][3]};
    *(float4*)(Op + (size_t)(m0 + tm + x) * E + n0 + tn) = o;
  }
}

__global__ __launch_bounds__(128) void out_combine_kernel(
    const float* __restrict__ OoPart, const float* __restrict__ bo,
    float* __restrict__ out) {
  const int s = blockIdx.x;
  const int e = threadIdx.x * 4;
  float4 o = *(const float4*)(bo + e);
  #pragma unroll
  for (int x = 0; x < 4; ++x) {
    float4 p = *(const float4*)(OoPart + (size_t)x * S * E + s * E + e);
    o.x += p.x; o.y += p.y; o.z += p.z; o.w += p.w;
  }
  *(float4*)(out + s * E + e) = o;
}

// ---------------------------------------------------------------------------
// Launch
// ---------------------------------------------------------------------------
extern "C" void kernel_launch(void* const* d_in, const int* in_sizes, int n_in,
                              void* d_out, int out_size, void* d_ws, size_t ws_size,
                              hipStream_t stream) {
  const float* x    = (const float*)d_in[0];
  const float* Wq   = (const float*)d_in[1];
  const float* bq   = (const float*)d_in[2];
  const float* Wk   = (const float*)d_in[3];
  const float* bk   = (const float*)d_in[4];
  const float* Wv   = (const float*)d_in[5];
  const float* bv   = (const float*)d_in[6];
  const float* Wo   = (const float*)d_in[7];
  const float* bo   = (const float*)d_in[8];
  const float* iqW  = (const float*)d_in[9];
  const float* iqb  = (const float*)d_in[10];
  const float* ikW  = (const float*)d_in[11];
  const float* ikb  = (const float*)d_in[12];
  const float* wpW  = (const float*)d_in[13];
  const float* wpb  = (const float*)d_in[14];

  float* ws = (float*)d_ws;
  float* Qb   = ws;                    // S*E
  float* Khm  = Qb + S * E;            // S*E (head-major)
  float* Vhm  = Khm + S * E;           // S*E (head-major)
  float* QI   = Vhm + S * E;           // S*E
  float* KI   = QI + S * E;            // S*DK
  float* WI   = KI + S * DK;           // S*H
  float* ISC  = WI + S * H;            // S*S
  unsigned* Mask = (unsigned*)(ISC + S * S);  // S*24 words
  float* Sum  = (float*)(Mask + S * 24);      // H*S
  float* Opart = Sum + H * S;          // 4*S*E  (PV partials; reused as OoPart)
  float* OoPart = Opart;               //        (disjoint lifetimes)
  float* ATT  = Opart + 4 * S * E;     // S*E

  SegTable tab;
  tab.W[0] = Wq;  tab.b[0] = bq;
  tab.W[1] = Wk;  tab.b[1] = bk;
  tab.W[2] = Wv;  tab.b[2] = bv;
  tab.W[3] = iqW; tab.b[3] = iqb;
  tab.W[4] = ikW; tab.b[4] = ikb;
  tab.W[5] = wpW; tab.b[5] = wpb;

  // projections (internal split-K): 34 x 12 = 408 blocks x 512 threads
  fused_proj_kernel<<<dim3(34, S / TM), dim3(512), 0, stream>>>(
      x, tab, Qb, Khm, Vhm, QI, KI, WI);
  // indexer scores: 288 blocks
  indexer_kernel<<<dim3(S / 64, S / 32), dim3(256), 0, stream>>>(QI, KI, WI, ISC);
  // top-k per row (radix select; also zeroes Sum)
  topk_kernel<<<dim3(S), dim3(256), 0, stream>>>(ISC, Mask, Sum);
  // fused masked attention: (4 chunks, 24 s-tiles, 8 h) = 768 blocks
  sattn_kernel<<<dim3(4, S / 32, H), dim3(256), 0, stream>>>(
      Qb, Khm, Vhm, Mask, Opart, Sum);
  // normalize + combine partials
  combine_kernel<<<dim3(S), dim3(128), 0, stream>>>(Opart, Sum, ATT);
  // output projection: 8 x 12 x 4 = 384 blocks (split-K) + bias combine
  out_part_kernel<<<dim3(E / TN, S / TM, 4), dim3(256), 0, stream>>>(ATT, Wo, OoPart);
  out_combine_kernel<<<dim3(S), dim3(128), 0, stream>>>(OoPart, bo, (float*)d_out);
}

// Round 9
// 188.408 us; speedup vs baseline: 2.2405x; 1.0513x over previous
//
#include <hip/hip_runtime.h>
#include <hip/hip_bf16.h>
#include <math.h>

// Problem constants
#define S 768
#define E 512
#define H 8
#define DK 64
#define TOPK 384

typedef short bf16x8 __attribute__((ext_vector_type(8)));
typedef float f32x4 __attribute__((ext_vector_type(4)));

// ---------------------------------------------------------------------------
// fp32 <-> bf16 split helpers (round-to-nearest-even)
// ---------------------------------------------------------------------------
__device__ __forceinline__ unsigned short f2bf(float x) {
  unsigned u = __float_as_uint(x);
  unsigned r = u + 0x7FFFu + ((u >> 16) & 1u);
  return (unsigned short)(r >> 16);
}
__device__ __forceinline__ float bf2f(unsigned short h) {
  return __uint_as_float(((unsigned)h) << 16);
}
__device__ __forceinline__ void split1(float x, unsigned short& h, unsigned short& l) {
  h = f2bf(x);
  l = f2bf(x - bf2f(h));
}

// 3-term fp32-accurate bf16 MFMA: D += A*B with A=ah+al, B=bh+bl (drop al*bl)
__device__ __forceinline__ void mfma3(f32x4& d, bf16x8 ah, bf16x8 al,
                                      bf16x8 bh, bf16x8 bl) {
  d = __builtin_amdgcn_mfma_f32_16x16x32_bf16(ah, bh, d, 0, 0, 0);
  d = __builtin_amdgcn_mfma_f32_16x16x32_bf16(ah, bl, d, 0, 0, 0);
  d = __builtin_amdgcn_mfma_f32_16x16x32_bf16(al, bh, d, 0, 0, 0);
}

__device__ __forceinline__ bf16x8 ldfrag(const unsigned short* p) {
  return *reinterpret_cast<const bf16x8*>(p);
}

// ---------------------------------------------------------------------------
// prep: split x -> Xhi/Xlo; transpose+split W[k][n] -> WT[n][k] hi/lo.
// seg: 0=x(no transpose) 1=Wq 2=Wk 3=Wv 4=iqW 5=ikW 6=wpW(pad n to 64) 7=Wo
// ---------------------------------------------------------------------------
struct PrepTab {
  const float* src[8];
  unsigned short* hi[8];
  unsigned short* lo[8];
};

__global__ __launch_bounds__(256) void prep_kernel(PrepTab t) {
  const int seg = blockIdx.z;
  const int rows = (seg == 0) ? 768 : 512;
  const int cols = (seg == 5) ? 64 : ((seg == 6) ? 8 : 512);
  const int tx = (cols + 31) >> 5, ty = rows >> 5;
  if ((int)blockIdx.x >= tx || (int)blockIdx.y >= ty) return;
  const int r0 = blockIdx.y * 32, c0 = blockIdx.x * 32;
  const int tid = threadIdx.x;
  const int rl = tid >> 3, c4 = (tid & 7) << 2;
  const float* src = t.src[seg];
  if (seg == 0) {
    float4 v = *(const float4*)(src + (size_t)(r0 + rl) * cols + c0 + c4);
    unsigned short h[4], l[4];
    split1(v.x, h[0], l[0]); split1(v.y, h[1], l[1]);
    split1(v.z, h[2], l[2]); split1(v.w, h[3], l[3]);
    size_t off = (size_t)(r0 + rl) * cols + c0 + c4;
    *(ushort4*)(t.hi[seg] + off) = make_ushort4(h[0], h[1], h[2], h[3]);
    *(ushort4*)(t.lo[seg] + off) = make_ushort4(l[0], l[1], l[2], l[3]);
  } else {
    __shared__ float ts[32][33];
    #pragma unroll
    for (int j = 0; j < 4; ++j) {
      int c = c4 + j;
      ts[rl][c] = (c0 + c < cols) ? src[(size_t)(r0 + rl) * cols + c0 + c] : 0.0f;
    }
    __syncthreads();
    // dst[n][k]: n = c0 + rl, k = r0 + c4..c4+3, stride 512
    float v0 = ts[c4 + 0][rl], v1 = ts[c4 + 1][rl];
    float v2 = ts[c4 + 2][rl], v3 = ts[c4 + 3][rl];
    unsigned short h[4], l[4];
    split1(v0, h[0], l[0]); split1(v1, h[1], l[1]);
    split1(v2, h[2], l[2]); split1(v3, h[3], l[3]);
    size_t off = (size_t)(c0 + rl) * 512 + r0 + c4;
    *(ushort4*)(t.hi[seg] + off) = make_ushort4(h[0], h[1], h[2], h[3]);
    *(ushort4*)(t.lo[seg] + off) = make_ushort4(l[0], l[1], l[2], l[3]);
  }
}

// ---------------------------------------------------------------------------
// Fused projections via MFMA (no LDS, no barriers). 64x64 tile per block,
// 4 waves = 2x2 quadrants of 32x32. K=512. 3-term bf16 = fp32 accuracy.
// Epilogue routes per segment (Khm/Vhm head-major fp32; QI/KI as bf16 hi/lo).
// ---------------------------------------------------------------------------
struct ProjTab {
  const unsigned short* whi[6];
  const unsigned short* wlo[6];
  const float* bias[6];
};

__global__ __launch_bounds__(256) void proj_mfma_kernel(
    const unsigned short* __restrict__ Xhi, const unsigned short* __restrict__ Xlo,
    ProjTab pt,
    float* __restrict__ Qb, float* __restrict__ Khm, float* __restrict__ Vhm,
    unsigned short* __restrict__ QIhi, unsigned short* __restrict__ QIlo,
    unsigned short* __restrict__ KIhi, unsigned short* __restrict__ KIlo,
    float* __restrict__ WI) {
  const int bx = blockIdx.x;
  int seg, nt;
  if (bx < 32) { seg = bx >> 3; nt = bx & 7; }
  else         { seg = 4 + (bx - 32); nt = 0; }
  const int m0 = blockIdx.y * 64;
  const int n0 = nt * 64;                 // within-seg col base
  const int tid = threadIdx.x;
  const int lane = tid & 63;
  const int wave = tid >> 6;
  const int mq = (wave >> 1) << 5;        // 0 or 32
  const int nq = (wave & 1) << 5;
  const int l15 = lane & 15;
  const int q8 = (lane >> 4) << 3;
  const int q4 = (lane >> 4) << 2;
  const unsigned short* Whi = pt.whi[seg];
  const unsigned short* Wlo = pt.wlo[seg];

  const size_t arow0 = (size_t)(m0 + mq + l15) * 512;
  const size_t arow1 = (size_t)(m0 + mq + 16 + l15) * 512;
  const size_t brow0 = (size_t)(n0 + nq + l15) * 512;
  const size_t brow1 = (size_t)(n0 + nq + 16 + l15) * 512;

  f32x4 acc[2][2] = {};
  for (int k0 = 0; k0 < 512; k0 += 32) {
    const int ko = k0 + q8;
    bf16x8 ah0 = ldfrag(Xhi + arow0 + ko);
    bf16x8 al0 = ldfrag(Xlo + arow0 + ko);
    bf16x8 ah1 = ldfrag(Xhi + arow1 + ko);
    bf16x8 al1 = ldfrag(Xlo + arow1 + ko);
    bf16x8 bh0 = ldfrag(Whi + brow0 + ko);
    bf16x8 bl0 = ldfrag(Wlo + brow0 + ko);
    bf16x8 bh1 = ldfrag(Whi + brow1 + ko);
    bf16x8 bl1 = ldfrag(Wlo + brow1 + ko);
    mfma3(acc[0][0], ah0, al0, bh0, bl0);
    mfma3(acc[0][1], ah0, al0, bh1, bl1);
    mfma3(acc[1][0], ah1, al1, bh0, bl0);
    mfma3(acc[1][1], ah1, al1, bh1, bl1);
  }

  const float* bias = pt.bias[seg];
  #pragma unroll
  for (int ntt = 0; ntt < 2; ++ntt) {
    const int nloc = n0 + nq + ntt * 16 + l15;
    const float bv = (seg == 5 && nloc >= 8) ? 0.0f : bias[nloc];
    #pragma unroll
    for (int mt = 0; mt < 2; ++mt) {
      #pragma unroll
      for (int r = 0; r < 4; ++r) {
        const int m = m0 + mq + mt * 16 + q4 + r;
        const float v = acc[mt][ntt][r] + bv;
        if (seg == 0) {
          Qb[(size_t)m * 512 + nloc] = v;
        } else if (seg == 1) {
          Khm[(size_t)(nloc >> 6) * (S * DK) + (size_t)m * DK + (nloc & 63)] = v;
        } else if (seg == 2) {
          Vhm[(size_t)(nloc >> 6) * (S * DK) + (size_t)m * DK + (nloc & 63)] = v;
        } else if (seg == 3) {
          unsigned short h, l;
          split1(v, h, l);
          QIhi[(size_t)m * 512 + nloc] = h;
          QIlo[(size_t)m * 512 + nloc] = l;
        } else if (seg == 4) {
          unsigned short h, l;
          split1(v, h, l);
          KIhi[(size_t)m * 64 + nloc] = h;
          KIlo[(size_t)m * 64 + nloc] = l;
        } else {
          if (nloc < 8) WI[(size_t)m * 8 + nloc] = v;
        }
      }
    }
  }
}

// ---------------------------------------------------------------------------
// Indexer via MFMA: ISC[s][t] = sum_h relu(dot64(QI[s,h],KI[t])) * WI[s][h].
// 64x64 tile, 4 waves (2x2 quadrants). QI/KI already bf16 hi/lo, k-contig.
// ---------------------------------------------------------------------------
__global__ __launch_bounds__(256) void indexer_mfma_kernel(
    const unsigned short* __restrict__ QIhi, const unsigned short* __restrict__ QIlo,
    const unsigned short* __restrict__ KIhi, const unsigned short* __restrict__ KIlo,
    const float* __restrict__ WI, float* __restrict__ ISC) {
  __shared__ float wis[64][8];
  const int s0 = blockIdx.y * 64, t0 = blockIdx.x * 64;
  const int tid = threadIdx.x;
  const int lane = tid & 63;
  const int wave = tid >> 6;
  const int mq = (wave >> 1) << 5;
  const int nq = (wave & 1) << 5;
  const int l15 = lane & 15;
  const int q8 = (lane >> 4) << 3;
  const int q4 = (lane >> 4) << 2;
  for (int i = tid; i < 512; i += 256)
    wis[i >> 3][i & 7] = WI[(size_t)(s0 + (i >> 3)) * 8 + (i & 7)];
  __syncthreads();

  const size_t arow0 = (size_t)(s0 + mq + l15) * 512;
  const size_t arow1 = (size_t)(s0 + mq + 16 + l15) * 512;
  const size_t brow0 = (size_t)(t0 + nq + l15) * 64;
  const size_t brow1 = (size_t)(t0 + nq + 16 + l15) * 64;

  float accI[2][2][4] = {};
  for (int h = 0; h < H; ++h) {
    f32x4 d[2][2] = {};
    #pragma unroll
    for (int k0 = 0; k0 < 64; k0 += 32) {
      const int ka = h * 64 + k0 + q8;
      const int kb = k0 + q8;
      bf16x8 ah0 = ldfrag(QIhi + arow0 + ka);
      bf16x8 al0 = ldfrag(QIlo + arow0 + ka);
      bf16x8 ah1 = ldfrag(QIhi + arow1 + ka);
      bf16x8 al1 = ldfrag(QIlo + arow1 + ka);
      bf16x8 bh0 = ldfrag(KIhi + brow0 + kb);
      bf16x8 bl0 = ldfrag(KIlo + brow0 + kb);
      bf16x8 bh1 = ldfrag(KIhi + brow1 + kb);
      bf16x8 bl1 = ldfrag(KIlo + brow1 + kb);
      mfma3(d[0][0], ah0, al0, bh0, bl0);
      mfma3(d[0][1], ah0, al0, bh1, bl1);
      mfma3(d[1][0], ah1, al1, bh0, bl0);
      mfma3(d[1][1], ah1, al1, bh1, bl1);
    }
    #pragma unroll
    for (int mt = 0; mt < 2; ++mt) {
      #pragma unroll
      for (int r = 0; r < 4; ++r) {
        const float w = wis[mq + mt * 16 + q4 + r][h];
        accI[mt][0][r] = fmaf(fmaxf(d[mt][0][r], 0.0f), w, accI[mt][0][r]);
        accI[mt][1][r] = fmaf(fmaxf(d[mt][1][r], 0.0f), w, accI[mt][1][r]);
      }
    }
  }
  #pragma unroll
  for (int mt = 0; mt < 2; ++mt)
    #pragma unroll
    for (int ntt = 0; ntt < 2; ++ntt)
      #pragma unroll
      for (int r = 0; r < 4; ++r)
        ISC[(size_t)(s0 + mq + mt * 16 + q4 + r) * S + t0 + nq + ntt * 16 + l15] =
            accI[mt][ntt][r];
}

// ---------------------------------------------------------------------------
// Top-k via exact radix select (selection set == jax.lax.top_k stable ties).
// Emits 768-bit mask, zeroes Sum. (unchanged from round 8)
// ---------------------------------------------------------------------------
__global__ __launch_bounds__(256) void topk_kernel(
    const float* __restrict__ ISC, unsigned* __restrict__ Mask,
    float* __restrict__ Sum) {
  __shared__ unsigned ordv[768];
  __shared__ int hist[256];
  __shared__ int gsum[16];
  __shared__ int sc[256];
  __shared__ unsigned mw[24];
  __shared__ unsigned sh_prefix;
  __shared__ int sh_R;
  const int s = blockIdx.x;
  const int tid = threadIdx.x;
  for (int i = tid; i < 768; i += 256) {
    float f = ISC[s * 768 + i] + 0.0f;
    unsigned u = __float_as_uint(f);
    ordv[i] = (u & 0x80000000u) ? ~u : (u | 0x80000000u);
  }
  if (tid < 24) mw[tid] = 0u;
  if (tid < H) Sum[tid * S + s] = 0.0f;
  if (tid == 0) { sh_prefix = 0u; sh_R = TOPK; }
  __syncthreads();
  for (int pass = 0; pass < 4; ++pass) {
    const int shift = 24 - pass * 8;
    hist[tid] = 0;
    __syncthreads();
    const unsigned pm = (pass == 0) ? 0u : (0xFFFFFFFFu << (shift + 8));
    const unsigned pref = sh_prefix;
    for (int i = tid; i < 768; i += 256) {
      unsigned o = ordv[i];
      if ((o & pm) == pref) atomicAdd(&hist[(o >> shift) & 255], 1);
    }
    __syncthreads();
    if (tid < 16) {
      int t = 0;
      #pragma unroll
      for (int k = 0; k < 16; ++k) t += hist[tid * 16 + k];
      gsum[tid] = t;
    }
    __syncthreads();
    if (tid == 0) {
      int R = sh_R;
      int G = 0;
      int g = 15;
      for (; g > 0; --g) {
        if (G + gsum[g] >= R) break;
        G += gsum[g];
      }
      int b = 15;
      for (; b > 0; --b) {
        int c = hist[g * 16 + b];
        if (G + c >= R) break;
        G += c;
      }
      sh_prefix = sh_prefix | ((unsigned)(g * 16 + b) << shift);
      sh_R = R - G;
    }
    __syncthreads();
  }
  const unsigned thr = sh_prefix;
  const int need_eq = sh_R;
  const int base = tid * 3;
  unsigned o0 = ordv[base], o1 = ordv[base + 1], o2 = ordv[base + 2];
  int c = (o0 == thr) + (o1 == thr) + (o2 == thr);
  sc[tid] = c;
  __syncthreads();
  for (int off = 1; off < 256; off <<= 1) {
    int v = (tid >= off) ? sc[tid - off] : 0;
    __syncthreads();
    sc[tid] += v;
    __syncthreads();
  }
  int rank = sc[tid] - c;
  if (o0 > thr || (o0 == thr && rank < need_eq))
    atomicOr(&mw[base >> 5], 1u << (base & 31));
  if (o0 == thr) ++rank;
  if (o1 > thr || (o1 == thr && rank < need_eq))
    atomicOr(&mw[(base + 1) >> 5], 1u << ((base + 1) & 31));
  if (o1 == thr) ++rank;
  if (o2 > thr || (o2 == thr && rank < need_eq))
    atomicOr(&mw[(base + 2) >> 5], 1u << ((base + 2) & 31));
  __syncthreads();
  if (tid < 24) Mask[s * 24 + tid] = mw[tid];
}

// ---------------------------------------------------------------------------
// Fused masked attention (fp32 flash-style, unchanged from round 8).
// ---------------------------------------------------------------------------
__global__ __launch_bounds__(256) void sattn_kernel(
    const float* __restrict__ Q, const float* __restrict__ Khm,
    const float* __restrict__ Vhm, const unsigned* __restrict__ Mask,
    float* __restrict__ Opart, float* __restrict__ Sum) {
  __shared__ __align__(16) float Qs[32][DK + 4];
  __shared__ __align__(16) float Ks[16][DK + 4];
  __shared__ __align__(16) float Vs[16][DK + 4];
  __shared__ __align__(16) float Ps[16][36];
  __shared__ unsigned msk[32][6];
  __shared__ float rsum[8][32];
  const int ks = blockIdx.x;
  const int s0 = blockIdx.y * 32;
  const int h  = blockIdx.z;
  const int tid = threadIdx.x;
  const int tbase = ks * 192;
  #pragma unroll
  for (int j = 0; j < 2; ++j) {
    int idx = tid + j * 256;
    int r = idx >> 4, cc = idx & 15;
    *(float4*)&Qs[r][cc * 4] =
        *(const float4*)(Q + (s0 + r) * E + h * DK + cc * 4);
  }
  if (tid < 192) {
    int r = tid & 31, j = tid >> 5;
    msk[r][j] = Mask[(s0 + r) * 24 + (tbase >> 5) + j];
  }
  const int ssc = tid & 31;
  const int tg  = tid >> 5;
  const int si = (tid >> 4) << 1;
  const int td = (tid & 15) << 2;
  float psum = 0.0f;
  float a0[4] = {}, a1[4] = {};
  for (int kt = 0; kt < 12; ++kt) {
    const int trow = tbase + kt * 16;
    __syncthreads();
    {
      int r = tid >> 4, cc = tid & 15;
      *(float4*)&Ks[r][cc * 4] =
          *(const float4*)(Khm + (size_t)(h * S + trow + r) * DK + cc * 4);
      *(float4*)&Vs[r][cc * 4] =
          *(const float4*)(Vhm + (size_t)(h * S + trow + r) * DK + cc * 4);
    }
    __syncthreads();
    {
      const int t0 = tg * 2, t1 = t0 + 1;
      float d0 = 0.0f, d1 = 0.0f;
      #pragma unroll
      for (int c4 = 0; c4 < 16; ++c4) {
        float4 qv = *(const float4*)&Qs[ssc][c4 * 4];
        float4 k0 = *(const float4*)&Ks[t0][c4 * 4];
        float4 k1 = *(const float4*)&Ks[t1][c4 * 4];
        d0 = fmaf(qv.x, k0.x, d0); d0 = fmaf(qv.y, k0.y, d0);
        d0 = fmaf(qv.z, k0.z, d0); d0 = fmaf(qv.w, k0.w, d0);
        d1 = fmaf(qv.x, k1.x, d1); d1 = fmaf(qv.y, k1.y, d1);
        d1 = fmaf(qv.z, k1.z, d1); d1 = fmaf(qv.w, k1.w, d1);
      }
      int tt0 = kt * 16 + t0, tt1 = tt0 + 1;
      unsigned w0 = msk[ssc][tt0 >> 5];
      float e0 = ((w0 >> (tt0 & 31)) & 1u) ? __expf(d0 * 0.125f) : 0.0f;
      float e1 = ((w0 >> (tt1 & 31)) & 1u) ? __expf(d1 * 0.125f) : 0.0f;
      Ps[t0][ssc] = e0;
      Ps[t1][ssc] = e1;
      psum += e0 + e1;
    }
    __syncthreads();
    #pragma unroll
    for (int t = 0; t < 16; ++t) {
      float p0 = Ps[t][si];
      float p1 = Ps[t][si + 1];
      float4 v4 = *(const float4*)&Vs[t][td];
      a0[0] = fmaf(p0, v4.x, a0[0]); a0[1] = fmaf(p0, v4.y, a0[1]);
      a0[2] = fmaf(p0, v4.z, a0[2]); a0[3] = fmaf(p0, v4.w, a0[3]);
      a1[0] = fmaf(p1, v4.x, a1[0]); a1[1] = fmaf(p1, v4.y, a1[1]);
      a1[2] = fmaf(p1, v4.z, a1[2]); a1[3] = fmaf(p1, v4.w, a1[3]);
    }
  }
  rsum[tg][ssc] = psum;
  __syncthreads();
  if (tid < 32) {
    float t = 0.0f;
    #pragma unroll
    for (int g = 0; g < 8; ++g) t += rsum[g][tid];
    atomicAdd(&Sum[h * S + s0 + tid], t);
  }
  float* Op = Opart + (size_t)ks * S * E;
  float4 o0 = {a0[0], a0[1], a0[2], a0[3]};
  float4 o1 = {a1[0], a1[1], a1[2], a1[3]};
  *(float4*)(Op + (size_t)(s0 + si) * E + h * DK + td) = o0;
  *(float4*)(Op + (size_t)(s0 + si + 1) * E + h * DK + td) = o1;
}

// ---------------------------------------------------------------------------
// Combine PV partials, normalize, and emit ATT as bf16 hi/lo for the MFMA
// output projection.
// ---------------------------------------------------------------------------
__global__ __launch_bounds__(128) void combine_kernel(
    const float* __restrict__ Opart, const float* __restrict__ Sum,
    unsigned short* __restrict__ ATThi, unsigned short* __restrict__ ATTlo) {
  const int s = blockIdx.x;
  const int e = threadIdx.x * 4;
  const int h = e >> 6;
  const float inv = 1.0f / Sum[h * S + s];
  float4 o = {0.0f, 0.0f, 0.0f, 0.0f};
  #pragma unroll
  for (int x = 0; x < 4; ++x) {
    float4 p = *(const float4*)(Opart + (size_t)x * S * E + s * E + e);
    o.x += p.x; o.y += p.y; o.z += p.z; o.w += p.w;
  }
  o.x *= inv; o.y *= inv; o.z *= inv; o.w *= inv;
  unsigned short hh[4], ll[4];
  split1(o.x, hh[0], ll[0]); split1(o.y, hh[1], ll[1]);
  split1(o.z, hh[2], ll[2]); split1(o.w, hh[3], ll[3]);
  *(ushort4*)(ATThi + (size_t)s * 512 + e) = make_ushort4(hh[0], hh[1], hh[2], hh[3]);
  *(ushort4*)(ATTlo + (size_t)s * 512 + e) = make_ushort4(ll[0], ll[1], ll[2], ll[3]);
}

// ---------------------------------------------------------------------------
// Output projection via MFMA: one wave per 32x32 tile. out = ATT@Wo + bo.
// ---------------------------------------------------------------------------
__global__ __launch_bounds__(64) void out_mfma_kernel(
    const unsigned short* __restrict__ Ahi, const unsigned short* __restrict__ Alo,
    const unsigned short* __restrict__ WoThi, const unsigned short* __restrict__ WoTlo,
    const float* __restrict__ bo, float* __restrict__ out) {
  const int n0 = blockIdx.x * 32, m0 = blockIdx.y * 32;
  const int lane = threadIdx.x;
  const int l15 = lane & 15;
  const int q8 = (lane >> 4) << 3;
  const int q4 = (lane >> 4) << 2;
  const size_t arow0 = (size_t)(m0 + l15) * 512;
  const size_t arow1 = (size_t)(m0 + 16 + l15) * 512;
  const size_t brow0 = (size_t)(n0 + l15) * 512;
  const size_t brow1 = (size_t)(n0 + 16 + l15) * 512;
  f32x4 acc[2][2] = {};
  for (int k0 = 0; k0 < 512; k0 += 32) {
    const int ko = k0 + q8;
    bf16x8 ah0 = ldfrag(Ahi + arow0 + ko);
    bf16x8 al0 = ldfrag(Alo + arow0 + ko);
    bf16x8 ah1 = ldfrag(Ahi + arow1 + ko);
    bf16x8 al1 = ldfrag(Alo + arow1 + ko);
    bf16x8 bh0 = ldfrag(WoThi + brow0 + ko);
    bf16x8 bl0 = ldfrag(WoTlo + brow0 + ko);
    bf16x8 bh1 = ldfrag(WoThi + brow1 + ko);
    bf16x8 bl1 = ldfrag(WoTlo + brow1 + ko);
    mfma3(acc[0][0], ah0, al0, bh0, bl0);
    mfma3(acc[0][1], ah0, al0, bh1, bl1);
    mfma3(acc[1][0], ah1, al1, bh0, bl0);
    mfma3(acc[1][1], ah1, al1, bh1, bl1);
  }
  #pragma unroll
  for (int ntt = 0; ntt < 2; ++ntt) {
    const int n = n0 + ntt * 16 + l15;
    const float bv = bo[n];
    #pragma unroll
    for (int mt = 0; mt < 2; ++mt)
      #pragma unroll
      for (int r = 0; r < 4; ++r)
        out[(size_t)(m0 + mt * 16 + q4 + r) * 512 + n] = acc[mt][ntt][r] + bv;
  }
}

// ---------------------------------------------------------------------------
// Launch
// ---------------------------------------------------------------------------
extern "C" void kernel_launch(void* const* d_in, const int* in_sizes, int n_in,
                              void* d_out, int out_size, void* d_ws, size_t ws_size,
                              hipStream_t stream) {
  const float* x    = (const float*)d_in[0];
  const float* Wq   = (const float*)d_in[1];
  const float* bq   = (const float*)d_in[2];
  const float* Wk   = (const float*)d_in[3];
  const float* bk   = (const float*)d_in[4];
  const float* Wv   = (const float*)d_in[5];
  const float* bv   = (const float*)d_in[6];
  const float* Wo   = (const float*)d_in[7];
  const float* bo   = (const float*)d_in[8];
  const float* iqW  = (const float*)d_in[9];
  const float* iqb  = (const float*)d_in[10];
  const float* ikW  = (const float*)d_in[11];
  const float* ikb  = (const float*)d_in[12];
  const float* wpW  = (const float*)d_in[13];
  const float* wpb  = (const float*)d_in[14];

  float* ws = (float*)d_ws;
  float* Qb   = ws;                         // S*E fp32
  float* Khm  = Qb + S * E;                 // S*E fp32 head-major
  float* Vhm  = Khm + S * E;                // S*E fp32 head-major
  float* WI   = Vhm + S * E;                // S*H fp32
  float* ISC  = WI + S * H;                 // S*S fp32
  unsigned* Mask = (unsigned*)(ISC + S * S);  // S*24
  float* Sum  = (float*)(Mask + S * 24);    // H*S
  float* Opart = Sum + H * S;               // 4*S*E fp32
  unsigned short* u = (unsigned short*)(Opart + 4 * S * E);
  unsigned short* Xhi  = u;             u += S * E;
  unsigned short* Xlo  = u;             u += S * E;
  unsigned short* QIhi = u;             u += S * E;
  unsigned short* QIlo = u;             u += S * E;
  unsigned short* KIhi = u;             u += S * DK;
  unsigned short* KIlo = u;             u += S * DK;
  unsigned short* ATThi = u;            u += S * E;
  unsigned short* ATTlo = u;            u += S * E;
  unsigned short* WTq_hi = u;           u += E * E;
  unsigned short* WTk_hi = u;           u += E * E;
  unsigned short* WTv_hi = u;           u += E * E;
  unsigned short* WTiq_hi = u;          u += E * E;
  unsigned short* WTik_hi = u;          u += 64 * E;
  unsigned short* WTwp_hi = u;          u += 64 * E;
  unsigned short* WTo_hi = u;           u += E * E;
  unsigned short* WTq_lo = u;           u += E * E;
  unsigned short* WTk_lo = u;           u += E * E;
  unsigned short* WTv_lo = u;           u += E * E;
  unsigned short* WTiq_lo = u;          u += E * E;
  unsigned short* WTik_lo = u;          u += 64 * E;
  unsigned short* WTwp_lo = u;          u += 64 * E;
  unsigned short* WTo_lo = u;           u += E * E;

  PrepTab prep;
  prep.src[0] = x;    prep.hi[0] = Xhi;     prep.lo[0] = Xlo;
  prep.src[1] = Wq;   prep.hi[1] = WTq_hi;  prep.lo[1] = WTq_lo;
  prep.src[2] = Wk;   prep.hi[2] = WTk_hi;  prep.lo[2] = WTk_lo;
  prep.src[3] = Wv;   prep.hi[3] = WTv_hi;  prep.lo[3] = WTv_lo;
  prep.src[4] = iqW;  prep.hi[4] = WTiq_hi; prep.lo[4] = WTiq_lo;
  prep.src[5] = ikW;  prep.hi[5] = WTik_hi; prep.lo[5] = WTik_lo;
  prep.src[6] = wpW;  prep.hi[6] = WTwp_hi; prep.lo[6] = WTwp_lo;
  prep.src[7] = Wo;   prep.hi[7] = WTo_hi;  prep.lo[7] = WTo_lo;

  ProjTab pt;
  pt.whi[0] = WTq_hi;  pt.wlo[0] = WTq_lo;  pt.bias[0] = bq;
  pt.whi[1] = WTk_hi;  pt.wlo[1] = WTk_lo;  pt.bias[1] = bk;
  pt.whi[2] = WTv_hi;  pt.wlo[2] = WTv_lo;  pt.bias[2] = bv;
  pt.whi[3] = WTiq_hi; pt.wlo[3] = WTiq_lo; pt.bias[3] = iqb;
  pt.whi[4] = WTik_hi; pt.wlo[4] = WTik_lo; pt.bias[4] = ikb;
  pt.whi[5] = WTwp_hi; pt.wlo[5] = WTwp_lo; pt.bias[5] = wpb;

  // 1) split x + transpose/split all weight matrices
  prep_kernel<<<dim3(16, 24, 8), dim3(256), 0, stream>>>(prep);
  // 2) all 6 projections via MFMA: 34 x 12 blocks
  proj_mfma_kernel<<<dim3(34, S / 64), dim3(256), 0, stream>>>(
      Xhi, Xlo, pt, Qb, Khm, Vhm, QIhi, QIlo, KIhi, KIlo, WI);
  // 3) indexer scores via MFMA: 12 x 12 blocks
  indexer_mfma_kernel<<<dim3(S / 64, S / 64), dim3(256), 0, stream>>>(
      QIhi, QIlo, KIhi, KIlo, WI, ISC);
  // 4) top-k per row (radix select; zeroes Sum)
  topk_kernel<<<dim3(S), dim3(256), 0, stream>>>(ISC, Mask, Sum);
  // 5) fused masked attention: (4 chunks, 24 s-tiles, 8 h)
  sattn_kernel<<<dim3(4, S / 32, H), dim3(256), 0, stream>>>(
      Qb, Khm, Vhm, Mask, Opart, Sum);
  // 6) combine + normalize + cast ATT to bf16 hi/lo
  combine_kernel<<<dim3(S), dim3(128), 0, stream>>>(Opart, Sum, ATThi, ATTlo);
  // 7) output projection via MFMA: (16 n, 24 m) one-wave blocks
  out_mfma_kernel<<<dim3(16, 24), dim3(64), 0, stream>>>(
      ATThi, ATTlo, WTo_hi, WTo_lo, bo, (float*)d_out);
}